// Round 3
// baseline (394.412 us; speedup 1.0000x reference)
//
#include <hip/hip_runtime.h>

typedef unsigned short u16;
typedef unsigned int u32;
typedef unsigned long long u64;

#define NB 4
#define NTOK 12544
#define NBHD 48
#define DIM 256
#define OUTD 512
#define KEEPN 3136
#define SAMPLEN 2352
#define RESN 784
#define GW 112
#define POSN (NB * KEEPN * 2)   // 25088 floats
#define QTR (NTOK / 4)          // 3136

#define BLKM 128
#define BLKN 256
#define BROW 40                 // padded B-tile row (u16)

__device__ __forceinline__ u16 f2bf(float f) {
    union { u32 i; float f; } v; v.f = f;
    return (u16)((v.i + 0x7FFFu + ((v.i >> 16) & 1u)) >> 16);
}

typedef __bf16 bf16x8 __attribute__((ext_vector_type(8)));
typedef float floatx4 __attribute__((ext_vector_type(4)));

// key: descending order == top_k order; ties -> lower n first
__device__ __forceinline__ u64 make_key(float lp, int n) {
    int i = n / GW, j = n % GW;
    float f = lp * 4.0f;                          // lp_s (f32, bit-exact vs ref)
    if (((i | j) & 1) == 0) f = 1.0f + f;         // grid_prob (stride 2)
    if (((i | j) & 3) == 0) f = f + (-100.0f);    // reserve penalty (stride 4)
    union { float f; u32 u; } v; v.f = f;
    u32 m = (v.u & 0x80000000u) ? ~v.u : (v.u | 0x80000000u);  // monotone map
    return (((u64)m) << 32) | (u64)(0xFFFFFFFFu - (u32)n);
}

// ---- K1: build sort keys ---------------------------------------------------
__global__ __launch_bounds__(256) void key_kernel(
    const float* __restrict__ lprob, u64* __restrict__ keys) {
    int g = blockIdx.x * 256 + threadIdx.x;      // 50176 = 196*256
    int n = g % NTOK;
    keys[g] = make_key(lprob[g], n);
}

// ---- K2: partial rank counts (work split 4-way over z) ---------------------
__global__ __launch_bounds__(256) void partial_rank_kernel(
    const u64* __restrict__ keys, u32* __restrict__ part) {
    int b = blockIdx.y, z = blockIdx.z;
    int n = blockIdx.x * 256 + threadIdx.x;      // NTOK = 49*256
    u64 my = keys[b * NTOK + n];
    const u64* kb = keys + b * NTOK + z * QTR;   // uniform addresses -> s_load
    u32 cnt = 0;
    for (int t = 0; t < QTR; t += 8) {
#pragma unroll
        for (int j = 0; j < 8; ++j) cnt += (kb[t + j] > my) ? 1u : 0u;
    }
    part[(z * NB + b) * NTOK + n] = cnt;
}

// ---- K3: finalize -> write pos_k (sample slots by rank + reserve slots) ----
__global__ __launch_bounds__(256) void finalize_kernel(
    const u32* __restrict__ part, float* __restrict__ pos_out) {
    int b = blockIdx.y;
    int n = blockIdx.x * 256 + threadIdx.x;
    int g = b * NTOK + n;
    u32 rank = part[g] + part[(NB + b) * NTOK + n] +
               part[(2 * NB + b) * NTOK + n] + part[(3 * NB + b) * NTOK + n];
    int i = n / GW, j = n % GW;
    if (rank < SAMPLEN) {
        int slot = b * KEEPN + (int)rank;
        pos_out[slot * 2 + 0] = (float)i;
        pos_out[slot * 2 + 1] = (float)j;
    }
    if (((i | j) & 3) == 0) {                    // reserve token, ascending n
        int r = (i >> 2) * 28 + (j >> 2);
        int slot = b * KEEPN + SAMPLEN + r;
        pos_out[slot * 2 + 0] = (float)i;
        pos_out[slot * 2 + 1] = (float)j;
    }
}

// ---- K4: gather + weight-net + weighted-sum + LN -> X row (bf16, in-place) -
__global__ __launch_bounds__(256) void token_kernel(
    const float* __restrict__ pos_in, float* __restrict__ out,
    const int* __restrict__ member_idx, const int* __restrict__ pe_idx,
    const float* __restrict__ cmask, const float* __restrict__ lprob,
    const float* __restrict__ feat, const float* __restrict__ pre_table,
    const float* __restrict__ w1, const float* __restrict__ b1,
    const float* __restrict__ g1, const float* __restrict__ bb1,
    const float* __restrict__ norm_g, const float* __restrict__ norm_b) {
    int t = blockIdx.x;                 // 0..12543
    int b = t / KEEPN;
    int tid = threadIdx.x;
    __shared__ int mem_s[NBHD];
    __shared__ float4 w_s[NBHD];
    __shared__ float red[10];

    int i0 = (int)pos_in[t * 2 + 0];
    int j0 = (int)pos_in[t * 2 + 1];
    int n_src = i0 * GW + j0;

    if (tid < NBHD) {
        int e = (b * NTOK + n_src) * NBHD + tid;
        int mem = member_idx[e];
        int pe = pe_idx[e];
        float cm = cmask[e];
        float lpe = lprob[b * NTOK + mem];
        float z[4];
#pragma unroll
        for (int m = 0; m < 4; ++m) {
            float acc = b1[m];
#pragma unroll
            for (int d = 0; d < 5; ++d) acc += pre_table[pe * 5 + d] * w1[d * 4 + m];
            z[m] = acc;
        }
        float mean = (z[0] + z[1] + z[2] + z[3]) * 0.25f;
        float var = 0.0f;
#pragma unroll
        for (int m = 0; m < 4; ++m) { float d = z[m] - mean; var += d * d; }
        float rstd = rsqrtf(var * 0.25f + 1e-5f);
        float sc = lpe * cm;
        float wv[4];
#pragma unroll
        for (int m = 0; m < 4; ++m) {
            float y = (z[m] - mean) * rstd * g1[m] + bb1[m];
            wv[m] = 0.5f * y * (1.0f + erff(y * 0.70710678118654752f)) * sc;
        }
        w_s[tid] = make_float4(wv[0], wv[1], wv[2], wv[3]);
        mem_s[tid] = mem;
    }
    __syncthreads();

    float a0 = 0.f, a1 = 0.f, a2 = 0.f, a3 = 0.f;
    const float* fb = feat + (size_t)b * NTOK * DIM + tid;
#pragma unroll 8
    for (int k = 0; k < NBHD; ++k) {
        float g = fb[(size_t)mem_s[k] * DIM];
        float4 w = w_s[k];
        a0 += w.x * g; a1 += w.y * g; a2 += w.z * g; a3 += w.w * g;
    }
    // LN over 1024 (4 per thread)
    float s1 = a0 + a1 + a2 + a3;
    float s2 = a0 * a0 + a1 * a1 + a2 * a2 + a3 * a3;
#pragma unroll
    for (int off = 32; off > 0; off >>= 1) {
        s1 += __shfl_down(s1, off, 64);
        s2 += __shfl_down(s2, off, 64);
    }
    int wave = tid >> 6, lane = tid & 63;
    if (lane == 0) { red[wave] = s1; red[4 + wave] = s2; }
    __syncthreads();
    if (tid == 0) {
        float S = red[0] + red[1] + red[2] + red[3];
        float Q = red[4] + red[5] + red[6] + red[7];
        float mean = S * (1.0f / 1024.0f);
        float var = fmaxf(Q * (1.0f / 1024.0f) - mean * mean, 0.0f);
        red[8] = mean; red[9] = rsqrtf(var + 1e-5f);
    }
    __syncthreads();
    float mean = red[8], rstd = red[9];
    float acc4[4] = {a0, a1, a2, a3};
    // pack LN'd row as 1024 bf16 into this row's 2048-byte output slot
    u16* Xp = (u16*)(out + (size_t)t * OUTD);
#pragma unroll
    for (int m = 0; m < 4; ++m) {
        int cc = m * 256 + tid;
        float v = (acc4[m] - mean) * rstd * norm_g[cc] + norm_b[cc];
        Xp[cc] = f2bf(v);
    }
}

// ---- K5: in-place GEMM  X(12544x1024 bf16) @ lin_w(1024x512 f32) + lin_b ---
__global__ __launch_bounds__(256) void gemm_kernel(
    const float* __restrict__ lin_w, const float* __restrict__ lin_b,
    float* __restrict__ out) {
    __shared__ __align__(16) u16 Bs[BLKN * BROW];    // 20 KB
    int tile_m = blockIdx.x;        // 98
    int nblk = blockIdx.y;          // 2
    int tid = threadIdx.x;
    int wave = tid >> 6, lane = tid & 63;
    int l15 = lane & 15, quad = lane >> 4;

    const u16* Xbase = (const u16*)out;   // bf16-packed X rows (in-place)
    floatx4 acc[8][4] = {};

    for (int kk = 0; kk < 1024; kk += 32) {
        __syncthreads();
        // stage Bs[n_local][k] = bf16(lin_w[kk+k][nblk*256+n_local])
#pragma unroll
        for (int it = 0; it < 4; ++it) {
            int task = it * 256 + tid;      // 0..1023
            int kp = task >> 6;             // 0..15 -> k = 2*kp
            int ng = task & 63;             // 0..63 -> n_local = ng*4..+3
            int k = kp * 2;
            int n0 = nblk * BLKN + ng * 4;
            float4 fa = *(const float4*)&lin_w[(size_t)(kk + k) * OUTD + n0];
            float4 fb = *(const float4*)&lin_w[(size_t)(kk + k + 1) * OUTD + n0];
            u16* bp = &Bs[(ng * 4) * BROW + k];
            *(u32*)(bp + 0 * BROW) = (u32)f2bf(fa.x) | ((u32)f2bf(fb.x) << 16);
            *(u32*)(bp + 1 * BROW) = (u32)f2bf(fa.y) | ((u32)f2bf(fb.y) << 16);
            *(u32*)(bp + 2 * BROW) = (u32)f2bf(fa.z) | ((u32)f2bf(fb.z) << 16);
            *(u32*)(bp + 3 * BROW) = (u32)f2bf(fa.w) | ((u32)f2bf(fb.w) << 16);
        }
        __syncthreads();
        bf16x8 bfrag[4];
#pragma unroll
        for (int ni = 0; ni < 4; ++ni)
            bfrag[ni] = *(const bf16x8*)&Bs[(wave * 64 + ni * 16 + l15) * BROW + quad * 8];
#pragma unroll
        for (int mi = 0; mi < 8; ++mi) {
            int row = tile_m * BLKM + mi * 16 + l15;
            bf16x8 af = *(const bf16x8*)&Xbase[(size_t)row * 1024 + kk + quad * 8];
#pragma unroll
            for (int ni = 0; ni < 4; ++ni)
                acc[mi][ni] = __builtin_amdgcn_mfma_f32_16x16x32_bf16(
                    af, bfrag[ni], acc[mi][ni], 0, 0, 0);
        }
    }
    __syncthreads();   // all X reads (all waves) complete before overwrite
#pragma unroll
    for (int mi = 0; mi < 8; ++mi)
#pragma unroll
        for (int ni = 0; ni < 4; ++ni) {
            int col = nblk * BLKN + wave * 64 + ni * 16 + l15;
            float bias = lin_b[col];
#pragma unroll
            for (int reg = 0; reg < 4; ++reg) {
                int row = tile_m * BLKM + mi * 16 + quad * 4 + reg;
                out[(size_t)row * OUTD + col] = acc[mi][ni][reg] + bias;
            }
        }
}

extern "C" void kernel_launch(void* const* d_in, const int* in_sizes, int n_in,
                              void* d_out, int out_size, void* d_ws, size_t ws_size,
                              hipStream_t stream) {
    const float* feat     = (const float*)d_in[1];
    const int* member_idx = (const int*)d_in[2];
    const float* cmask    = (const float*)d_in[3];
    const float* lprob    = (const float*)d_in[4];
    const int* pe_idx     = (const int*)d_in[6];
    const float* pre_table= (const float*)d_in[8];
    const float* w1       = (const float*)d_in[9];
    const float* b1       = (const float*)d_in[10];
    const float* g1       = (const float*)d_in[11];
    const float* bb1      = (const float*)d_in[12];
    const float* norm_g   = (const float*)d_in[13];
    const float* norm_b   = (const float*)d_in[14];
    const float* lin_w    = (const float*)d_in[15];
    const float* lin_b    = (const float*)d_in[16];

    float* pos_out = (float*)d_out;              // 25088 floats
    float* out     = pos_out + POSN;             // 6422528 floats

    // scratch lives in the (not yet written) out region; the token kernel
    // overwrites it AFTER the ranking phase has finished with it.
    u64* keys = (u64*)out;                               // 401408 B
    u32* part = (u32*)((char*)out + 401408);             // 802816 B

    key_kernel<<<(NB * NTOK) / 256, 256, 0, stream>>>(lprob, keys);
    partial_rank_kernel<<<dim3(49, NB, 4), 256, 0, stream>>>(keys, part);
    finalize_kernel<<<dim3(49, NB), 256, 0, stream>>>(part, pos_out);
    token_kernel<<<NB * KEEPN, 256, 0, stream>>>(
        pos_out, out, member_idx, pe_idx, cmask, lprob, feat, pre_table,
        w1, b1, g1, bb1, norm_g, norm_b);
    gemm_kernel<<<dim3(98, 2), 256, 0, stream>>>(lin_w, lin_b, out);
}

// Round 4
// 357.341 us; speedup vs baseline: 1.1037x; 1.1037x over previous
//
#include <hip/hip_runtime.h>

typedef unsigned short u16;
typedef unsigned int u32;
typedef unsigned long long u64;

#define NB 4
#define NTOK 12544
#define NBHD 48
#define DIM 256
#define OUTD 512
#define KEEPN 3136
#define SAMPLEN 2352
#define RESN 784
#define GW 112
#define POSN (NB * KEEPN * 2)   // 25088 floats
#define QTR (NTOK / 4)          // 3136

// fallback in-place GEMM tiling
#define BLKM 128
#define BLKN 256
#define BROW 40

// ws fast-path layout (bytes)
#define FEATB_BYTES (25690112ull)                 // 4*12544*256*2
#define XWS_BYTES   (25690112ull)                 // 12544*1024*2
#define LINT_BYTES  (1048576ull)                  // 512*1024*2
#define KEYS_BYTES  (401408ull)
#define PART_BYTES  (802816ull)
#define WS_NEED (FEATB_BYTES + XWS_BYTES + LINT_BYTES + KEYS_BYTES + PART_BYTES)

__device__ __forceinline__ float bf2f(u16 u) {
    union { u32 i; float f; } v; v.i = ((u32)u) << 16; return v.f;
}
__device__ __forceinline__ u16 f2bf(float f) {
    union { u32 i; float f; } v; v.f = f;
    return (u16)((v.i + 0x7FFFu + ((v.i >> 16) & 1u)) >> 16);
}

typedef __bf16 bf16x8 __attribute__((ext_vector_type(8)));
typedef float floatx4 __attribute__((ext_vector_type(4)));

// key: descending order == top_k order; ties -> lower n first
__device__ __forceinline__ u64 make_key(float lp, int n) {
    int i = n / GW, j = n % GW;
    float f = lp * 4.0f;
    if (((i | j) & 1) == 0) f = 1.0f + f;
    if (((i | j) & 3) == 0) f = f + (-100.0f);
    union { float f; u32 u; } v; v.f = f;
    u32 m = (v.u & 0x80000000u) ? ~v.u : (v.u | 0x80000000u);
    return (((u64)m) << 32) | (u64)(0xFFFFFFFFu - (u32)n);
}

// ---- convert feat f32 -> bf16 ---------------------------------------------
__global__ __launch_bounds__(256) void feat_cvt_kernel(
    const float* __restrict__ feat, u16* __restrict__ featb) {
    int t = blockIdx.x * 256 + threadIdx.x;       // 3,211,264 float4 exactly
    float4 v = ((const float4*)feat)[t];
    u64 w = (u64)f2bf(v.x) | ((u64)f2bf(v.y) << 16) |
            ((u64)f2bf(v.z) << 32) | ((u64)f2bf(v.w) << 48);
    ((u64*)featb)[t] = w;
}

// ---- convert + transpose lin_w (1024x512 f32) -> linT (512x1024 bf16) -----
__global__ __launch_bounds__(256) void linT_cvt_kernel(
    const float* __restrict__ lin_w, u16* __restrict__ linT) {
    __shared__ u16 T[64 * 65];
    int k0 = blockIdx.x * 64, n0 = blockIdx.y * 64;
    int t = threadIdx.x;
    int r = t >> 2, c4 = (t & 3) * 16;
#pragma unroll
    for (int i = 0; i < 4; ++i) {
        float4 v = *(const float4*)&lin_w[(size_t)(k0 + r) * OUTD + n0 + c4 + i * 4];
        T[(c4 + i * 4 + 0) * 65 + r] = f2bf(v.x);
        T[(c4 + i * 4 + 1) * 65 + r] = f2bf(v.y);
        T[(c4 + i * 4 + 2) * 65 + r] = f2bf(v.z);
        T[(c4 + i * 4 + 3) * 65 + r] = f2bf(v.w);
    }
    __syncthreads();
    int nl = t >> 2, kc = (t & 3) * 16;
    union { uint4 v[2]; u16 h[16]; } u;
#pragma unroll
    for (int i = 0; i < 16; ++i) u.h[i] = T[nl * 65 + kc + i];
    u16* dst = &linT[(size_t)(n0 + nl) * 1024 + k0 + kc];
    *(uint4*)(dst + 0) = u.v[0];
    *(uint4*)(dst + 8) = u.v[1];
}

// ---- K1: build sort keys ---------------------------------------------------
__global__ __launch_bounds__(256) void key_kernel(
    const float* __restrict__ lprob, u64* __restrict__ keys) {
    int g = blockIdx.x * 256 + threadIdx.x;
    keys[g] = make_key(lprob[g], g % NTOK);
}

// ---- K2: partial rank counts ----------------------------------------------
__global__ __launch_bounds__(256) void partial_rank_kernel(
    const u64* __restrict__ keys, u32* __restrict__ part) {
    int b = blockIdx.y, z = blockIdx.z;
    int n = blockIdx.x * 256 + threadIdx.x;
    u64 my = keys[b * NTOK + n];
    const u64* kb = keys + b * NTOK + z * QTR;
    u32 cnt = 0;
    for (int t = 0; t < QTR; t += 8) {
#pragma unroll
        for (int j = 0; j < 8; ++j) cnt += (kb[t + j] > my) ? 1u : 0u;
    }
    part[(z * NB + b) * NTOK + n] = cnt;
}

// ---- K3: finalize -> pos_k -------------------------------------------------
__global__ __launch_bounds__(256) void finalize_kernel(
    const u32* __restrict__ part, float* __restrict__ pos_out) {
    int b = blockIdx.y;
    int n = blockIdx.x * 256 + threadIdx.x;
    int g = b * NTOK + n;
    u32 rank = part[g] + part[(NB + b) * NTOK + n] +
               part[(2 * NB + b) * NTOK + n] + part[(3 * NB + b) * NTOK + n];
    int i = n / GW, j = n % GW;
    if (rank < SAMPLEN) {
        int slot = b * KEEPN + (int)rank;
        pos_out[slot * 2 + 0] = (float)i;
        pos_out[slot * 2 + 1] = (float)j;
    }
    if (((i | j) & 3) == 0) {
        int r = (i >> 2) * 28 + (j >> 2);
        int slot = b * KEEPN + SAMPLEN + r;
        pos_out[slot * 2 + 0] = (float)i;
        pos_out[slot * 2 + 1] = (float)j;
    }
}

// ---- K4: gather + weight-net + weighted-sum + LN -> X row (bf16) ----------
template <bool BF>
__global__ __launch_bounds__(256) void token_kernel(
    const float* __restrict__ pos_in, u16* __restrict__ xdst,
    const int* __restrict__ member_idx, const int* __restrict__ pe_idx,
    const float* __restrict__ cmask, const float* __restrict__ lprob,
    const float* __restrict__ featf, const u16* __restrict__ featb,
    const float* __restrict__ pre_table,
    const float* __restrict__ w1, const float* __restrict__ b1,
    const float* __restrict__ g1, const float* __restrict__ bb1,
    const float* __restrict__ norm_g, const float* __restrict__ norm_b) {
    int t = blockIdx.x;
    int b = t / KEEPN;
    int tid = threadIdx.x;
    __shared__ int mem_s[NBHD];
    __shared__ float4 w_s[NBHD];
    __shared__ float red[10];

    int n_src = (int)pos_in[t * 2 + 0] * GW + (int)pos_in[t * 2 + 1];

    if (tid < NBHD) {
        int e = (b * NTOK + n_src) * NBHD + tid;
        int mem = member_idx[e];
        int pe = pe_idx[e];
        float cm = cmask[e];
        float lpe = lprob[b * NTOK + mem];
        float z[4];
#pragma unroll
        for (int m = 0; m < 4; ++m) {
            float acc = b1[m];
#pragma unroll
            for (int d = 0; d < 5; ++d) acc += pre_table[pe * 5 + d] * w1[d * 4 + m];
            z[m] = acc;
        }
        float mean = (z[0] + z[1] + z[2] + z[3]) * 0.25f;
        float var = 0.0f;
#pragma unroll
        for (int m = 0; m < 4; ++m) { float d = z[m] - mean; var += d * d; }
        float rstd = rsqrtf(var * 0.25f + 1e-5f);
        float sc = lpe * cm;
        float wv[4];
#pragma unroll
        for (int m = 0; m < 4; ++m) {
            float y = (z[m] - mean) * rstd * g1[m] + bb1[m];
            wv[m] = 0.5f * y * (1.0f + erff(y * 0.70710678118654752f)) * sc;
        }
        w_s[tid] = make_float4(wv[0], wv[1], wv[2], wv[3]);
        mem_s[tid] = mem;
    }
    __syncthreads();

    float a0 = 0.f, a1 = 0.f, a2 = 0.f, a3 = 0.f;
    size_t base = (size_t)b * NTOK * DIM + tid;
#pragma unroll 8
    for (int k = 0; k < NBHD; ++k) {
        size_t off = base + (size_t)mem_s[k] * DIM;
        float g = BF ? bf2f(featb[off]) : featf[off];
        float4 w = w_s[k];
        a0 += w.x * g; a1 += w.y * g; a2 += w.z * g; a3 += w.w * g;
    }
    float s1 = a0 + a1 + a2 + a3;
    float s2 = a0 * a0 + a1 * a1 + a2 * a2 + a3 * a3;
#pragma unroll
    for (int off = 32; off > 0; off >>= 1) {
        s1 += __shfl_down(s1, off, 64);
        s2 += __shfl_down(s2, off, 64);
    }
    int wave = tid >> 6, lane = tid & 63;
    if (lane == 0) { red[wave] = s1; red[4 + wave] = s2; }
    __syncthreads();
    if (tid == 0) {
        float S = red[0] + red[1] + red[2] + red[3];
        float Q = red[4] + red[5] + red[6] + red[7];
        float mean = S * (1.0f / 1024.0f);
        float var = fmaxf(Q * (1.0f / 1024.0f) - mean * mean, 0.0f);
        red[8] = mean; red[9] = rsqrtf(var + 1e-5f);
    }
    __syncthreads();
    float mean = red[8], rstd = red[9];
    float acc4[4] = {a0, a1, a2, a3};
    u16* Xp = xdst + (size_t)t * 1024;
#pragma unroll
    for (int m = 0; m < 4; ++m) {
        int cc = m * 256 + tid;
        float v = (acc4[m] - mean) * rstd * norm_g[cc] + norm_b[cc];
        Xp[cc] = f2bf(v);
    }
}

// ---- K5 fast: LDS-free GEMM  X(12544x1024 bf16) @ linT(512x1024 bf16)^T ---
__global__ __launch_bounds__(256) void gemm_fast_kernel(
    const u16* __restrict__ xws, const u16* __restrict__ linT,
    const float* __restrict__ lin_b, float* __restrict__ out) {
    int tid = threadIdx.x;
    int wave = tid >> 6, lane = tid & 63;
    int l15 = lane & 15, quad = lane >> 4;
    int r0 = blockIdx.x * 64 + (wave >> 1) * 32;       // 196 m-tiles
    int c0 = blockIdx.y * 128 + (wave & 1) * 64;       // 4 n-tiles

    const u16* Abase = xws + (size_t)(r0 + l15) * 1024 + quad * 8;
    const u16* Bbase = linT + (size_t)(c0 + l15) * 1024 + quad * 8;

    floatx4 acc[2][4] = {};
#pragma unroll 4
    for (int kk = 0; kk < 1024; kk += 32) {
        bf16x8 af[2], bf[4];
#pragma unroll
        for (int mi = 0; mi < 2; ++mi)
            af[mi] = *(const bf16x8*)(Abase + (size_t)mi * 16 * 1024 + kk);
#pragma unroll
        for (int ni = 0; ni < 4; ++ni)
            bf[ni] = *(const bf16x8*)(Bbase + (size_t)ni * 16 * 1024 + kk);
#pragma unroll
        for (int mi = 0; mi < 2; ++mi)
#pragma unroll
            for (int ni = 0; ni < 4; ++ni)
                acc[mi][ni] = __builtin_amdgcn_mfma_f32_16x16x32_bf16(
                    af[mi], bf[ni], acc[mi][ni], 0, 0, 0);
    }
#pragma unroll
    for (int ni = 0; ni < 4; ++ni) {
        int col = c0 + ni * 16 + l15;
        float bias = lin_b[col];
#pragma unroll
        for (int mi = 0; mi < 2; ++mi)
#pragma unroll
            for (int reg = 0; reg < 4; ++reg) {
                int row = r0 + mi * 16 + quad * 4 + reg;
                out[(size_t)row * OUTD + col] = acc[mi][ni][reg] + bias;
            }
    }
}

// ---- K5 fallback: in-place GEMM (round-3 proven) --------------------------
__global__ __launch_bounds__(256) void gemm_inplace_kernel(
    const float* __restrict__ lin_w, const float* __restrict__ lin_b,
    float* __restrict__ out) {
    __shared__ __align__(16) u16 Bs[BLKN * BROW];
    int tile_m = blockIdx.x;
    int nblk = blockIdx.y;
    int tid = threadIdx.x;
    int wave = tid >> 6, lane = tid & 63;
    int l15 = lane & 15, quad = lane >> 4;

    const u16* Xbase = (const u16*)out;
    floatx4 acc[8][4] = {};

    for (int kk = 0; kk < 1024; kk += 32) {
        __syncthreads();
#pragma unroll
        for (int it = 0; it < 4; ++it) {
            int task = it * 256 + tid;
            int kp = task >> 6;
            int ng = task & 63;
            int k = kp * 2;
            int n0 = nblk * BLKN + ng * 4;
            float4 fa = *(const float4*)&lin_w[(size_t)(kk + k) * OUTD + n0];
            float4 fb = *(const float4*)&lin_w[(size_t)(kk + k + 1) * OUTD + n0];
            u16* bp = &Bs[(ng * 4) * BROW + k];
            *(u32*)(bp + 0 * BROW) = (u32)f2bf(fa.x) | ((u32)f2bf(fb.x) << 16);
            *(u32*)(bp + 1 * BROW) = (u32)f2bf(fa.y) | ((u32)f2bf(fb.y) << 16);
            *(u32*)(bp + 2 * BROW) = (u32)f2bf(fa.z) | ((u32)f2bf(fb.z) << 16);
            *(u32*)(bp + 3 * BROW) = (u32)f2bf(fa.w) | ((u32)f2bf(fb.w) << 16);
        }
        __syncthreads();
        bf16x8 bfrag[4];
#pragma unroll
        for (int ni = 0; ni < 4; ++ni)
            bfrag[ni] = *(const bf16x8*)&Bs[(wave * 64 + ni * 16 + l15) * BROW + quad * 8];
#pragma unroll
        for (int mi = 0; mi < 8; ++mi) {
            int row = tile_m * BLKM + mi * 16 + l15;
            bf16x8 af = *(const bf16x8*)&Xbase[(size_t)row * 1024 + kk + quad * 8];
#pragma unroll
            for (int ni = 0; ni < 4; ++ni)
                acc[mi][ni] = __builtin_amdgcn_mfma_f32_16x16x32_bf16(
                    af, bfrag[ni], acc[mi][ni], 0, 0, 0);
        }
    }
    __syncthreads();
#pragma unroll
    for (int mi = 0; mi < 8; ++mi)
#pragma unroll
        for (int ni = 0; ni < 4; ++ni) {
            int col = nblk * BLKN + wave * 64 + ni * 16 + l15;
            float bias = lin_b[col];
#pragma unroll
            for (int reg = 0; reg < 4; ++reg) {
                int row = tile_m * BLKM + mi * 16 + quad * 4 + reg;
                out[(size_t)row * OUTD + col] = acc[mi][ni][reg] + bias;
            }
        }
}

extern "C" void kernel_launch(void* const* d_in, const int* in_sizes, int n_in,
                              void* d_out, int out_size, void* d_ws, size_t ws_size,
                              hipStream_t stream) {
    const float* feat     = (const float*)d_in[1];
    const int* member_idx = (const int*)d_in[2];
    const float* cmask    = (const float*)d_in[3];
    const float* lprob    = (const float*)d_in[4];
    const int* pe_idx     = (const int*)d_in[6];
    const float* pre_table= (const float*)d_in[8];
    const float* w1       = (const float*)d_in[9];
    const float* b1       = (const float*)d_in[10];
    const float* g1       = (const float*)d_in[11];
    const float* bb1      = (const float*)d_in[12];
    const float* norm_g   = (const float*)d_in[13];
    const float* norm_b   = (const float*)d_in[14];
    const float* lin_w    = (const float*)d_in[15];
    const float* lin_b    = (const float*)d_in[16];

    float* pos_out = (float*)d_out;
    float* out     = pos_out + POSN;

    if (ws_size >= WS_NEED) {
        // ---------------- fast path: big workspace ----------------
        char* ws = (char*)d_ws;
        u16* featb = (u16*)ws;
        u16* xws   = (u16*)(ws + FEATB_BYTES);
        u16* linT  = (u16*)(ws + FEATB_BYTES + XWS_BYTES);
        u64* keys  = (u64*)(ws + FEATB_BYTES + XWS_BYTES + LINT_BYTES);
        u32* part  = (u32*)(ws + FEATB_BYTES + XWS_BYTES + LINT_BYTES + KEYS_BYTES);

        feat_cvt_kernel<<<12544, 256, 0, stream>>>(feat, featb);
        linT_cvt_kernel<<<dim3(16, 8), 256, 0, stream>>>(lin_w, linT);
        key_kernel<<<(NB * NTOK) / 256, 256, 0, stream>>>(lprob, keys);
        partial_rank_kernel<<<dim3(49, NB, 4), 256, 0, stream>>>(keys, part);
        finalize_kernel<<<dim3(49, NB), 256, 0, stream>>>(part, pos_out);
        token_kernel<true><<<NB * KEEPN, 256, 0, stream>>>(
            pos_out, xws, member_idx, pe_idx, cmask, lprob, feat, featb,
            pre_table, w1, b1, g1, bb1, norm_g, norm_b);
        gemm_fast_kernel<<<dim3(196, 4), 256, 0, stream>>>(xws, linT, lin_b, out);
    } else {
        // ---------------- fallback: zero workspace (round-3 scheme) ----------
        u64* keys = (u64*)out;
        u32* part = (u32*)((char*)out + 401408);

        key_kernel<<<(NB * NTOK) / 256, 256, 0, stream>>>(lprob, keys);
        partial_rank_kernel<<<dim3(49, NB, 4), 256, 0, stream>>>(keys, part);
        finalize_kernel<<<dim3(49, NB), 256, 0, stream>>>(part, pos_out);
        token_kernel<false><<<NB * KEEPN, 256, 0, stream>>>(
            pos_out, (u16*)out, member_idx, pe_idx, cmask, lprob, feat, nullptr,
            pre_table, w1, b1, g1, bb1, norm_g, norm_b);
        gemm_inplace_kernel<<<dim3(98, 2), 256, 0, stream>>>(lin_w, lin_b, out);
    }
}

// Round 5
// 297.202 us; speedup vs baseline: 1.3271x; 1.2024x over previous
//
#include <hip/hip_runtime.h>

typedef unsigned short u16;
typedef unsigned int u32;
typedef unsigned long long u64;

#define NB 4
#define NTOK 12544
#define NBHD 48
#define DIM 256
#define OUTD 512
#define KEEPN 3136
#define SAMPLEN 2352
#define RESN 784
#define GW 112
#define POSN (NB * KEEPN * 2)   // 25088 floats
#define QTR (NTOK / 4)          // 3136

// fallback in-place GEMM tiling
#define BLKM 128
#define BLKN 256
#define BROW 40

// ws fast-path layout (bytes)
#define FEATB_BYTES (25690112ull)                 // 4*12544*256*2
#define XWS_BYTES   (25690112ull)                 // 12544*1024*2
#define LINT_BYTES  (1048576ull)                  // 512*1024*2
#define KEYS_BYTES  (401408ull)
#define PART_BYTES  (802816ull)
#define WS_NEED (FEATB_BYTES + XWS_BYTES + LINT_BYTES + KEYS_BYTES + PART_BYTES)

__device__ __forceinline__ float bf2f(u16 u) {
    union { u32 i; float f; } v; v.i = ((u32)u) << 16; return v.f;
}
__device__ __forceinline__ float asf(u32 u) {
    union { u32 i; float f; } v; v.i = u; return v.f;
}
__device__ __forceinline__ u16 f2bf(float f) {
    union { u32 i; float f; } v; v.f = f;
    return (u16)((v.i + 0x7FFFu + ((v.i >> 16) & 1u)) >> 16);
}

typedef __bf16 bf16x8 __attribute__((ext_vector_type(8)));
typedef float floatx4 __attribute__((ext_vector_type(4)));

// key: descending order == top_k order; ties -> lower n first
__device__ __forceinline__ u64 make_key(float lp, int n) {
    int i = n / GW, j = n % GW;
    float f = lp * 4.0f;
    if (((i | j) & 1) == 0) f = 1.0f + f;
    if (((i | j) & 3) == 0) f = f + (-100.0f);
    union { float f; u32 u; } v; v.f = f;
    u32 m = (v.u & 0x80000000u) ? ~v.u : (v.u | 0x80000000u);
    return (((u64)m) << 32) | (u64)(0xFFFFFFFFu - (u32)n);
}

// ---- convert feat f32 -> bf16 ---------------------------------------------
__global__ __launch_bounds__(256) void feat_cvt_kernel(
    const float* __restrict__ feat, u16* __restrict__ featb) {
    int t = blockIdx.x * 256 + threadIdx.x;
    float4 v = ((const float4*)feat)[t];
    u64 w = (u64)f2bf(v.x) | ((u64)f2bf(v.y) << 16) |
            ((u64)f2bf(v.z) << 32) | ((u64)f2bf(v.w) << 48);
    ((u64*)featb)[t] = w;
}

// ---- convert + transpose lin_w (1024x512 f32) -> linT (512x1024 bf16) -----
__global__ __launch_bounds__(256) void linT_cvt_kernel(
    const float* __restrict__ lin_w, u16* __restrict__ linT) {
    __shared__ u16 T[64 * 65];
    int k0 = blockIdx.x * 64, n0 = blockIdx.y * 64;
    int t = threadIdx.x;
    int r = t >> 2, c4 = (t & 3) * 16;
#pragma unroll
    for (int i = 0; i < 4; ++i) {
        float4 v = *(const float4*)&lin_w[(size_t)(k0 + r) * OUTD + n0 + c4 + i * 4];
        T[(c4 + i * 4 + 0) * 65 + r] = f2bf(v.x);
        T[(c4 + i * 4 + 1) * 65 + r] = f2bf(v.y);
        T[(c4 + i * 4 + 2) * 65 + r] = f2bf(v.z);
        T[(c4 + i * 4 + 3) * 65 + r] = f2bf(v.w);
    }
    __syncthreads();
    int nl = t >> 2, kc = (t & 3) * 16;
    union { uint4 v[2]; u16 h[16]; } u;
#pragma unroll
    for (int i = 0; i < 16; ++i) u.h[i] = T[nl * 65 + kc + i];
    u16* dst = &linT[(size_t)(n0 + nl) * 1024 + k0 + kc];
    *(uint4*)(dst + 0) = u.v[0];
    *(uint4*)(dst + 8) = u.v[1];
}

// ---- K1: build sort keys ---------------------------------------------------
__global__ __launch_bounds__(256) void key_kernel(
    const float* __restrict__ lprob, u64* __restrict__ keys) {
    int g = blockIdx.x * 256 + threadIdx.x;
    keys[g] = make_key(lprob[g], g % NTOK);
}

// ---- K2: partial rank counts ----------------------------------------------
__global__ __launch_bounds__(256) void partial_rank_kernel(
    const u64* __restrict__ keys, u32* __restrict__ part) {
    int b = blockIdx.y, z = blockIdx.z;
    int n = blockIdx.x * 256 + threadIdx.x;
    u64 my = keys[b * NTOK + n];
    const u64* kb = keys + b * NTOK + z * QTR;
    u32 cnt = 0;
    for (int t = 0; t < QTR; t += 8) {
#pragma unroll
        for (int j = 0; j < 8; ++j) cnt += (kb[t + j] > my) ? 1u : 0u;
    }
    part[(z * NB + b) * NTOK + n] = cnt;
}

// ---- K3: finalize -> pos_k -------------------------------------------------
__global__ __launch_bounds__(256) void finalize_kernel(
    const u32* __restrict__ part, float* __restrict__ pos_out) {
    int b = blockIdx.y;
    int n = blockIdx.x * 256 + threadIdx.x;
    int g = b * NTOK + n;
    u32 rank = part[g] + part[(NB + b) * NTOK + n] +
               part[(2 * NB + b) * NTOK + n] + part[(3 * NB + b) * NTOK + n];
    int i = n / GW, j = n % GW;
    if (rank < SAMPLEN) {
        int slot = b * KEEPN + (int)rank;
        pos_out[slot * 2 + 0] = (float)i;
        pos_out[slot * 2 + 1] = (float)j;
    }
    if (((i | j) & 3) == 0) {
        int r = (i >> 2) * 28 + (j >> 2);
        int slot = b * KEEPN + SAMPLEN + r;
        pos_out[slot * 2 + 0] = (float)i;
        pos_out[slot * 2 + 1] = (float)j;
    }
}

// ---- K4 v2: row-per-wave gather + weight-net + LN -> X row (bf16) ---------
__global__ __launch_bounds__(256) void token_v2_kernel(
    const float* __restrict__ pos_in, u16* __restrict__ xdst,
    const int* __restrict__ member_idx, const int* __restrict__ pe_idx,
    const float* __restrict__ cmask, const float* __restrict__ lprob,
    const u16* __restrict__ featb, const float* __restrict__ pre_table,
    const float* __restrict__ w1, const float* __restrict__ b1,
    const float* __restrict__ g1, const float* __restrict__ bb1,
    const float* __restrict__ norm_g, const float* __restrict__ norm_b) {
    int t = blockIdx.x;
    int b = t / KEEPN;
    int tid = threadIdx.x;
    int wave = tid >> 6, lane = tid & 63;
    __shared__ int mem_s[NBHD];
    __shared__ float4 w_s[NBHD];
    __shared__ float partials[4 * 64 * 16];   // [wave][lane][j*4+m] 16 KB
    __shared__ float red[10];

    int n_src = (int)pos_in[t * 2 + 0] * GW + (int)pos_in[t * 2 + 1];

    if (tid < NBHD) {
        int e = (b * NTOK + n_src) * NBHD + tid;
        int mem = member_idx[e];
        int pe = pe_idx[e];
        float cm = cmask[e];
        float lpe = lprob[b * NTOK + mem];
        float z[4];
#pragma unroll
        for (int m = 0; m < 4; ++m) {
            float acc = b1[m];
#pragma unroll
            for (int d = 0; d < 5; ++d) acc += pre_table[pe * 5 + d] * w1[d * 4 + m];
            z[m] = acc;
        }
        float mean = (z[0] + z[1] + z[2] + z[3]) * 0.25f;
        float var = 0.0f;
#pragma unroll
        for (int m = 0; m < 4; ++m) { float d = z[m] - mean; var += d * d; }
        float rstd = rsqrtf(var * 0.25f + 1e-5f);
        float sc = lpe * cm;
        float wv[4];
#pragma unroll
        for (int m = 0; m < 4; ++m) {
            float y = (z[m] - mean) * rstd * g1[m] + bb1[m];
            wv[m] = 0.5f * y * (1.0f + erff(y * 0.70710678118654752f)) * sc;
        }
        w_s[tid] = make_float4(wv[0], wv[1], wv[2], wv[3]);
        mem_s[tid] = mem;
    }
    __syncthreads();

    // wave w gathers rows k = w*12 .. w*12+11; lane holds channels lane*4..+3
    float acc[16];
#pragma unroll
    for (int i = 0; i < 16; ++i) acc[i] = 0.0f;
    const u16* fbase = featb + (size_t)b * NTOK * DIM + lane * 4;
    int k0 = wave * 12;
#pragma unroll
    for (int kk = 0; kk < 12; ++kk) {
        int k = k0 + kk;
        uint2 d = *(const uint2*)(fbase + (size_t)mem_s[k] * DIM);
        float4 w = w_s[k];
        float c0 = asf(d.x << 16);
        float c1 = asf(d.x & 0xFFFF0000u);
        float c2 = asf(d.y << 16);
        float c3 = asf(d.y & 0xFFFF0000u);
        acc[0]  += w.x * c0; acc[1]  += w.y * c0; acc[2]  += w.z * c0; acc[3]  += w.w * c0;
        acc[4]  += w.x * c1; acc[5]  += w.y * c1; acc[6]  += w.z * c1; acc[7]  += w.w * c1;
        acc[8]  += w.x * c2; acc[9]  += w.y * c2; acc[10] += w.z * c2; acc[11] += w.w * c2;
        acc[12] += w.x * c3; acc[13] += w.y * c3; acc[14] += w.z * c3; acc[15] += w.w * c3;
    }
    float* pp = &partials[(wave * 64 + lane) * 16];
#pragma unroll
    for (int i = 0; i < 4; ++i)
        *(float4*)(pp + i * 4) = make_float4(acc[i * 4], acc[i * 4 + 1],
                                             acc[i * 4 + 2], acc[i * 4 + 3]);
    __syncthreads();

    // thread tid owns channel c = tid; reduce over 4 waves
    int c = tid;
    float a[4] = {0.f, 0.f, 0.f, 0.f};
#pragma unroll
    for (int w = 0; w < 4; ++w) {
        float4 v = *(const float4*)&partials[(w * 64 + (c >> 2)) * 16 + (c & 3) * 4];
        a[0] += v.x; a[1] += v.y; a[2] += v.z; a[3] += v.w;
    }

    // LN over 1024 (4 per thread)
    float s1 = a[0] + a[1] + a[2] + a[3];
    float s2 = a[0] * a[0] + a[1] * a[1] + a[2] * a[2] + a[3] * a[3];
#pragma unroll
    for (int off = 32; off > 0; off >>= 1) {
        s1 += __shfl_down(s1, off, 64);
        s2 += __shfl_down(s2, off, 64);
    }
    if (lane == 0) { red[wave] = s1; red[4 + wave] = s2; }
    __syncthreads();
    if (tid == 0) {
        float S = red[0] + red[1] + red[2] + red[3];
        float Q = red[4] + red[5] + red[6] + red[7];
        float mean = S * (1.0f / 1024.0f);
        float var = fmaxf(Q * (1.0f / 1024.0f) - mean * mean, 0.0f);
        red[8] = mean; red[9] = rsqrtf(var + 1e-5f);
    }
    __syncthreads();
    float mean = red[8], rstd = red[9];
    u16* Xp = xdst + (size_t)t * 1024;
#pragma unroll
    for (int m = 0; m < 4; ++m) {
        int cc = m * 256 + c;
        float v = (a[m] - mean) * rstd * norm_g[cc] + norm_b[cc];
        Xp[cc] = f2bf(v);
    }
}

// ---- K5 v2: LDS-tiled GEMM X(12544x1024 bf16) @ linT(512x1024 bf16)^T -----
#define GROW 40   // padded LDS row stride (halves)
__global__ __launch_bounds__(256) void gemm_tile_kernel(
    const u16* __restrict__ xws, const u16* __restrict__ linT,
    const float* __restrict__ lin_b, float* __restrict__ out) {
    __shared__ __align__(16) u16 As[64 * GROW];     // 5.1 KB
    __shared__ __align__(16) u16 Bs[128 * GROW];    // 10.2 KB
    int tid = threadIdx.x;
    int wave = tid >> 6, lane = tid & 63;
    int l15 = lane & 15, quad = lane >> 4;
    int wm = wave >> 1, wn = wave & 1;
    int m0 = blockIdx.x * 64, n0 = blockIdx.y * 128;
    int sr = tid >> 2, sk = (tid & 3) * 8;

    const u16* Ap  = xws + (size_t)(m0 + sr) * 1024 + sk;
    const u16* Bp0 = linT + (size_t)(n0 + sr) * 1024 + sk;
    const u16* Bp1 = linT + (size_t)(n0 + 64 + sr) * 1024 + sk;

    floatx4 acc[2][4] = {};
    for (int kk = 0; kk < 1024; kk += 32) {
        uint4 av = *(const uint4*)(Ap + kk);
        uint4 b0 = *(const uint4*)(Bp0 + kk);
        uint4 b1 = *(const uint4*)(Bp1 + kk);
        __syncthreads();
        *(uint4*)&As[sr * GROW + sk] = av;
        *(uint4*)&Bs[sr * GROW + sk] = b0;
        *(uint4*)&Bs[(64 + sr) * GROW + sk] = b1;
        __syncthreads();
        bf16x8 af[2], bfv[4];
#pragma unroll
        for (int mi = 0; mi < 2; ++mi)
            af[mi] = *(const bf16x8*)&As[(wm * 32 + mi * 16 + l15) * GROW + quad * 8];
#pragma unroll
        for (int ni = 0; ni < 4; ++ni)
            bfv[ni] = *(const bf16x8*)&Bs[(wn * 64 + ni * 16 + l15) * GROW + quad * 8];
#pragma unroll
        for (int mi = 0; mi < 2; ++mi)
#pragma unroll
            for (int ni = 0; ni < 4; ++ni)
                acc[mi][ni] = __builtin_amdgcn_mfma_f32_16x16x32_bf16(
                    af[mi], bfv[ni], acc[mi][ni], 0, 0, 0);
    }
#pragma unroll
    for (int ni = 0; ni < 4; ++ni) {
        int col = n0 + wn * 64 + ni * 16 + l15;
        float bias = lin_b[col];
#pragma unroll
        for (int mi = 0; mi < 2; ++mi)
#pragma unroll
            for (int reg = 0; reg < 4; ++reg) {
                int row = m0 + wm * 32 + mi * 16 + quad * 4 + reg;
                out[(size_t)row * OUTD + col] = acc[mi][ni][reg] + bias;
            }
    }
}

// ---- fallback kernels (zero-workspace, round-3 proven) --------------------
__global__ __launch_bounds__(256) void token_fb_kernel(
    const float* __restrict__ pos_in, u16* __restrict__ xdst,
    const int* __restrict__ member_idx, const int* __restrict__ pe_idx,
    const float* __restrict__ cmask, const float* __restrict__ lprob,
    const float* __restrict__ featf, const float* __restrict__ pre_table,
    const float* __restrict__ w1, const float* __restrict__ b1,
    const float* __restrict__ g1, const float* __restrict__ bb1,
    const float* __restrict__ norm_g, const float* __restrict__ norm_b) {
    int t = blockIdx.x;
    int b = t / KEEPN;
    int tid = threadIdx.x;
    __shared__ int mem_s[NBHD];
    __shared__ float4 w_s[NBHD];
    __shared__ float red[10];

    int n_src = (int)pos_in[t * 2 + 0] * GW + (int)pos_in[t * 2 + 1];

    if (tid < NBHD) {
        int e = (b * NTOK + n_src) * NBHD + tid;
        int mem = member_idx[e];
        int pe = pe_idx[e];
        float cm = cmask[e];
        float lpe = lprob[b * NTOK + mem];
        float z[4];
#pragma unroll
        for (int m = 0; m < 4; ++m) {
            float acc = b1[m];
#pragma unroll
            for (int d = 0; d < 5; ++d) acc += pre_table[pe * 5 + d] * w1[d * 4 + m];
            z[m] = acc;
        }
        float mean = (z[0] + z[1] + z[2] + z[3]) * 0.25f;
        float var = 0.0f;
#pragma unroll
        for (int m = 0; m < 4; ++m) { float d = z[m] - mean; var += d * d; }
        float rstd = rsqrtf(var * 0.25f + 1e-5f);
        float sc = lpe * cm;
        float wv[4];
#pragma unroll
        for (int m = 0; m < 4; ++m) {
            float y = (z[m] - mean) * rstd * g1[m] + bb1[m];
            wv[m] = 0.5f * y * (1.0f + erff(y * 0.70710678118654752f)) * sc;
        }
        w_s[tid] = make_float4(wv[0], wv[1], wv[2], wv[3]);
        mem_s[tid] = mem;
    }
    __syncthreads();

    float a0 = 0.f, a1 = 0.f, a2 = 0.f, a3 = 0.f;
    size_t base = (size_t)b * NTOK * DIM + tid;
#pragma unroll 8
    for (int k = 0; k < NBHD; ++k) {
        float g = featf[base + (size_t)mem_s[k] * DIM];
        float4 w = w_s[k];
        a0 += w.x * g; a1 += w.y * g; a2 += w.z * g; a3 += w.w * g;
    }
    float s1 = a0 + a1 + a2 + a3;
    float s2 = a0 * a0 + a1 * a1 + a2 * a2 + a3 * a3;
#pragma unroll
    for (int off = 32; off > 0; off >>= 1) {
        s1 += __shfl_down(s1, off, 64);
        s2 += __shfl_down(s2, off, 64);
    }
    int wave = tid >> 6, lane = tid & 63;
    if (lane == 0) { red[wave] = s1; red[4 + wave] = s2; }
    __syncthreads();
    if (tid == 0) {
        float S = red[0] + red[1] + red[2] + red[3];
        float Q = red[4] + red[5] + red[6] + red[7];
        float mean = S * (1.0f / 1024.0f);
        float var = fmaxf(Q * (1.0f / 1024.0f) - mean * mean, 0.0f);
        red[8] = mean; red[9] = rsqrtf(var + 1e-5f);
    }
    __syncthreads();
    float mean = red[8], rstd = red[9];
    float acc4[4] = {a0, a1, a2, a3};
    u16* Xp = xdst + (size_t)t * 1024;
#pragma unroll
    for (int m = 0; m < 4; ++m) {
        int cc = m * 256 + tid;
        float v = (acc4[m] - mean) * rstd * norm_g[cc] + norm_b[cc];
        Xp[cc] = f2bf(v);
    }
}

__global__ __launch_bounds__(256) void gemm_inplace_kernel(
    const float* __restrict__ lin_w, const float* __restrict__ lin_b,
    float* __restrict__ out) {
    __shared__ __align__(16) u16 Bs[BLKN * BROW];
    int tile_m = blockIdx.x;
    int nblk = blockIdx.y;
    int tid = threadIdx.x;
    int wave = tid >> 6, lane = tid & 63;
    int l15 = lane & 15, quad = lane >> 4;

    const u16* Xbase = (const u16*)out;
    floatx4 acc[8][4] = {};

    for (int kk = 0; kk < 1024; kk += 32) {
        __syncthreads();
#pragma unroll
        for (int it = 0; it < 4; ++it) {
            int task = it * 256 + tid;
            int kp = task >> 6;
            int ng = task & 63;
            int k = kp * 2;
            int n0 = nblk * BLKN + ng * 4;
            float4 fa = *(const float4*)&lin_w[(size_t)(kk + k) * OUTD + n0];
            float4 fb = *(const float4*)&lin_w[(size_t)(kk + k + 1) * OUTD + n0];
            u16* bp = &Bs[(ng * 4) * BROW + k];
            *(u32*)(bp + 0 * BROW) = (u32)f2bf(fa.x) | ((u32)f2bf(fb.x) << 16);
            *(u32*)(bp + 1 * BROW) = (u32)f2bf(fa.y) | ((u32)f2bf(fb.y) << 16);
            *(u32*)(bp + 2 * BROW) = (u32)f2bf(fa.z) | ((u32)f2bf(fb.z) << 16);
            *(u32*)(bp + 3 * BROW) = (u32)f2bf(fa.w) | ((u32)f2bf(fb.w) << 16);
        }
        __syncthreads();
        bf16x8 bfrag[4];
#pragma unroll
        for (int ni = 0; ni < 4; ++ni)
            bfrag[ni] = *(const bf16x8*)&Bs[(wave * 64 + ni * 16 + l15) * BROW + quad * 8];
#pragma unroll
        for (int mi = 0; mi < 8; ++mi) {
            int row = tile_m * BLKM + mi * 16 + l15;
            bf16x8 af = *(const bf16x8*)&Xbase[(size_t)row * 1024 + kk + quad * 8];
#pragma unroll
            for (int ni = 0; ni < 4; ++ni)
                acc[mi][ni] = __builtin_amdgcn_mfma_f32_16x16x32_bf16(
                    af, bfrag[ni], acc[mi][ni], 0, 0, 0);
        }
    }
    __syncthreads();
#pragma unroll
    for (int mi = 0; mi < 8; ++mi)
#pragma unroll
        for (int ni = 0; ni < 4; ++ni) {
            int col = nblk * BLKN + wave * 64 + ni * 16 + l15;
            float bias = lin_b[col];
#pragma unroll
            for (int reg = 0; reg < 4; ++reg) {
                int row = tile_m * BLKM + mi * 16 + quad * 4 + reg;
                out[(size_t)row * OUTD + col] = acc[mi][ni][reg] + bias;
            }
        }
}

extern "C" void kernel_launch(void* const* d_in, const int* in_sizes, int n_in,
                              void* d_out, int out_size, void* d_ws, size_t ws_size,
                              hipStream_t stream) {
    const float* feat     = (const float*)d_in[1];
    const int* member_idx = (const int*)d_in[2];
    const float* cmask    = (const float*)d_in[3];
    const float* lprob    = (const float*)d_in[4];
    const int* pe_idx     = (const int*)d_in[6];
    const float* pre_table= (const float*)d_in[8];
    const float* w1       = (const float*)d_in[9];
    const float* b1       = (const float*)d_in[10];
    const float* g1       = (const float*)d_in[11];
    const float* bb1      = (const float*)d_in[12];
    const float* norm_g   = (const float*)d_in[13];
    const float* norm_b   = (const float*)d_in[14];
    const float* lin_w    = (const float*)d_in[15];
    const float* lin_b    = (const float*)d_in[16];

    float* pos_out = (float*)d_out;
    float* out     = pos_out + POSN;

    if (ws_size >= WS_NEED) {
        char* ws = (char*)d_ws;
        u16* featb = (u16*)ws;
        u16* xws   = (u16*)(ws + FEATB_BYTES);
        u16* linT  = (u16*)(ws + FEATB_BYTES + XWS_BYTES);
        u64* keys  = (u64*)(ws + FEATB_BYTES + XWS_BYTES + LINT_BYTES);
        u32* part  = (u32*)(ws + FEATB_BYTES + XWS_BYTES + LINT_BYTES + KEYS_BYTES);

        feat_cvt_kernel<<<12544, 256, 0, stream>>>(feat, featb);
        linT_cvt_kernel<<<dim3(16, 8), 256, 0, stream>>>(lin_w, linT);
        key_kernel<<<(NB * NTOK) / 256, 256, 0, stream>>>(lprob, keys);
        partial_rank_kernel<<<dim3(49, NB, 4), 256, 0, stream>>>(keys, part);
        finalize_kernel<<<dim3(49, NB), 256, 0, stream>>>(part, pos_out);
        token_v2_kernel<<<NB * KEEPN, 256, 0, stream>>>(
            pos_out, xws, member_idx, pe_idx, cmask, lprob, featb,
            pre_table, w1, b1, g1, bb1, norm_g, norm_b);
        gemm_tile_kernel<<<dim3(196, 4), 256, 0, stream>>>(xws, linT, lin_b, out);
    } else {
        u64* keys = (u64*)out;
        u32* part = (u32*)((char*)out + 401408);

        key_kernel<<<(NB * NTOK) / 256, 256, 0, stream>>>(lprob, keys);
        partial_rank_kernel<<<dim3(49, NB, 4), 256, 0, stream>>>(keys, part);
        finalize_kernel<<<dim3(49, NB), 256, 0, stream>>>(part, pos_out);
        token_fb_kernel<<<NB * KEEPN, 256, 0, stream>>>(
            pos_out, (u16*)out, member_idx, pe_idx, cmask, lprob, feat,
            pre_table, w1, b1, g1, bb1, norm_g, norm_b);
        gemm_inplace_kernel<<<dim3(98, 2), 256, 0, stream>>>(lin_w, lin_b, out);
    }
}

// Round 6
// 254.401 us; speedup vs baseline: 1.5504x; 1.1682x over previous
//
#include <hip/hip_runtime.h>

typedef unsigned short u16;
typedef unsigned int u32;
typedef unsigned long long u64;

#define NB 4
#define NTOK 12544
#define NBHD 48
#define DIM 256
#define OUTD 512
#define KEEPN 3136
#define SAMPLEN 2352
#define RESN 784
#define GW 112
#define POSN (NB * KEEPN * 2)   // 25088 floats
#define QTR (NTOK / 4)          // 3136
#define NBKT 16384

// fallback in-place GEMM tiling
#define BLKM 128
#define BLKN 256
#define BROW 40

// ws fast-path layout (bytes)
#define FEATB_BYTES (25690112ull)                 // 4*12544*256*2
#define XWS_BYTES   (25690112ull)                 // 12544*1024*2
#define LINT_BYTES  (1048576ull)                  // 512*1024*2
#define KEYS_BYTES  (401408ull)                   // slots: 4*12544*8
#define PART_BYTES  (802816ull)                   // hist+base+cursor: 786432 used
#define WS_NEED (FEATB_BYTES + XWS_BYTES + LINT_BYTES + KEYS_BYTES + PART_BYTES)

__device__ __forceinline__ float bf2f(u16 u) {
    union { u32 i; float f; } v; v.i = ((u32)u) << 16; return v.f;
}
__device__ __forceinline__ float asf(u32 u) {
    union { u32 i; float f; } v; v.i = u; return v.f;
}
__device__ __forceinline__ u16 f2bf(float f) {
    union { u32 i; float f; } v; v.f = f;
    return (u16)((v.i + 0x7FFFu + ((v.i >> 16) & 1u)) >> 16);
}

typedef __bf16 bf16x8 __attribute__((ext_vector_type(8)));
typedef float floatx4 __attribute__((ext_vector_type(4)));

// final_prob, bit-exact vs reference f32 arithmetic
__device__ __forceinline__ float make_f(float lp, int n) {
    int i = n / GW, j = n % GW;
    float f = lp * 4.0f;
    if (((i | j) & 1) == 0) f = 1.0f + f;        // grid_prob (stride 2)
    if (((i | j) & 3) == 0) f = f + (-100.0f);   // reserve penalty (stride 4)
    return f;
}
// key: descending order == top_k order; ties -> lower n first
__device__ __forceinline__ u64 f_to_key(float f, int n) {
    union { float f; u32 u; } v; v.f = f;
    u32 m = (v.u & 0x80000000u) ? ~v.u : (v.u | 0x80000000u);
    return (((u64)m) << 32) | (u64)(0xFFFFFFFFu - (u32)n);
}
__device__ __forceinline__ int f_to_bucket(float f) {
    int b = (int)floorf(f * 3276.8f);            // monotone: [0,5) -> [0,16384)
    return b < 0 ? 0 : (b > NBKT - 1 ? NBKT - 1 : b);
}

// ---- convert feat f32 -> bf16 ---------------------------------------------
__global__ __launch_bounds__(256) void feat_cvt_kernel(
    const float* __restrict__ feat, u16* __restrict__ featb) {
    int t = blockIdx.x * 256 + threadIdx.x;
    float4 v = ((const float4*)feat)[t];
    u64 w = (u64)f2bf(v.x) | ((u64)f2bf(v.y) << 16) |
            ((u64)f2bf(v.z) << 32) | ((u64)f2bf(v.w) << 48);
    ((u64*)featb)[t] = w;
}

// ---- convert + transpose lin_w (1024x512 f32) -> linT (512x1024 bf16) -----
__global__ __launch_bounds__(256) void linT_cvt_kernel(
    const float* __restrict__ lin_w, u16* __restrict__ linT) {
    __shared__ u16 T[64 * 65];
    int k0 = blockIdx.x * 64, n0 = blockIdx.y * 64;
    int t = threadIdx.x;
    int r = t >> 2, c4 = (t & 3) * 16;
#pragma unroll
    for (int i = 0; i < 4; ++i) {
        float4 v = *(const float4*)&lin_w[(size_t)(k0 + r) * OUTD + n0 + c4 + i * 4];
        T[(c4 + i * 4 + 0) * 65 + r] = f2bf(v.x);
        T[(c4 + i * 4 + 1) * 65 + r] = f2bf(v.y);
        T[(c4 + i * 4 + 2) * 65 + r] = f2bf(v.z);
        T[(c4 + i * 4 + 3) * 65 + r] = f2bf(v.w);
    }
    __syncthreads();
    int nl = t >> 2, kc = (t & 3) * 16;
    union { uint4 v[2]; u16 h[16]; } u;
#pragma unroll
    for (int i = 0; i < 16; ++i) u.h[i] = T[nl * 65 + kc + i];
    u16* dst = &linT[(size_t)(n0 + nl) * 1024 + k0 + kc];
    *(uint4*)(dst + 0) = u.v[0];
    *(uint4*)(dst + 8) = u.v[1];
}

// ================= selection: exact counting-sort top-k =====================
__global__ __launch_bounds__(256) void zero_hist_kernel(u32* __restrict__ hist) {
    hist[blockIdx.x * 256 + threadIdx.x] = 0;      // grid 256 -> 65536
}

__global__ __launch_bounds__(256) void hist_kernel(
    const float* __restrict__ lprob, u32* __restrict__ hist) {
    int g = blockIdx.x * 256 + threadIdx.x;        // 196 blocks
    int b = g / NTOK, n = g % NTOK;
    int bkt = f_to_bucket(make_f(lprob[g], n));
    atomicAdd(&hist[b * NBKT + bkt], 1u);
}

// descending exclusive prefix: base[e] = #keys in buckets > e
__global__ __launch_bounds__(1024) void prefix_kernel(
    const u32* __restrict__ hist, u32* __restrict__ base, u32* __restrict__ cursor) {
    int b = blockIdx.x, t = threadIdx.x;
    const u32* h = hist + b * NBKT;
    u32 loc[16], own = 0;
#pragma unroll
    for (int i = 0; i < 16; ++i) { loc[i] = h[t * 16 + i]; own += loc[i]; }
    __shared__ u32 buf[2][1024];
    buf[0][t] = own;
    __syncthreads();
    int src = 0;
    for (int off = 1; off < 1024; off <<= 1) {
        u32 v = buf[src][t] + ((t + off < 1024) ? buf[src][t + off] : 0u);
        buf[src ^ 1][t] = v;
        src ^= 1;
        __syncthreads();
    }
    u32 above = buf[src][t] - own;                 // chunks strictly after t
    u32 suf = 0, bout[16];
    for (int i = 15; i >= 0; --i) { bout[i] = above + suf; suf += loc[i]; }
    u32* bb = base + b * NBKT;
    u32* cc = cursor + b * NBKT;
#pragma unroll
    for (int i = 0; i < 16; ++i) { bb[t * 16 + i] = bout[i]; cc[t * 16 + i] = bout[i]; }
}

__global__ __launch_bounds__(256) void scatter_kernel(
    const float* __restrict__ lprob, u32* __restrict__ cursor,
    u64* __restrict__ slots) {
    int g = blockIdx.x * 256 + threadIdx.x;
    int b = g / NTOK, n = g % NTOK;
    float f = make_f(lprob[g], n);
    int bkt = f_to_bucket(f);
    u32 s = atomicAdd(&cursor[b * NBKT + bkt], 1u);
    slots[b * NTOK + s] = f_to_key(f, n);
}

__global__ __launch_bounds__(256) void rank_finalize_kernel(
    const float* __restrict__ lprob, const u32* __restrict__ hist,
    const u32* __restrict__ base, const u64* __restrict__ slots,
    float* __restrict__ pos_out) {
    int g = blockIdx.x * 256 + threadIdx.x;
    int b = g / NTOK, n = g % NTOK;
    int i = n / GW, j = n % GW;
    if (((i | j) & 3) == 0) {
        // reserve token: rank >= 11760 > SAMPLEN always; fills fixed tail slot
        int r = (i >> 2) * 28 + (j >> 2);
        int slot = b * KEEPN + SAMPLEN + r;
        pos_out[slot * 2 + 0] = (float)i;
        pos_out[slot * 2 + 1] = (float)j;
        return;
    }
    float f = make_f(lprob[g], n);
    int bkt = f_to_bucket(f);
    u32 r0 = base[b * NBKT + bkt];
    if (r0 >= SAMPLEN) return;                     // whole bucket below cut
    u64 my = f_to_key(f, n);
    u32 cnt = hist[b * NBKT + bkt];
    const u64* sl = slots + b * NTOK + r0;
    u32 rank = r0;
    for (u32 s = 0; s < cnt; ++s) rank += (sl[s] > my) ? 1u : 0u;
    if (rank < SAMPLEN) {
        int slot = b * KEEPN + (int)rank;
        pos_out[slot * 2 + 0] = (float)i;
        pos_out[slot * 2 + 1] = (float)j;
    }
}

// ---- K4 v2: row-per-wave gather + weight-net + LN -> X row (bf16) ---------
__global__ __launch_bounds__(256) void token_v2_kernel(
    const float* __restrict__ pos_in, u16* __restrict__ xdst,
    const int* __restrict__ member_idx, const int* __restrict__ pe_idx,
    const float* __restrict__ cmask, const float* __restrict__ lprob,
    const u16* __restrict__ featb, const float* __restrict__ pre_table,
    const float* __restrict__ w1, const float* __restrict__ b1,
    const float* __restrict__ g1, const float* __restrict__ bb1,
    const float* __restrict__ norm_g, const float* __restrict__ norm_b) {
    int t = blockIdx.x;
    int b = t / KEEPN;
    int tid = threadIdx.x;
    int wave = tid >> 6, lane = tid & 63;
    __shared__ int mem_s[NBHD];
    __shared__ float4 w_s[NBHD];
    __shared__ float partials[4 * 64 * 16];   // [wave][lane][j*4+m] 16 KB
    __shared__ float red[10];

    int n_src = (int)pos_in[t * 2 + 0] * GW + (int)pos_in[t * 2 + 1];

    if (tid < NBHD) {
        int e = (b * NTOK + n_src) * NBHD + tid;
        int mem = member_idx[e];
        int pe = pe_idx[e];
        float cm = cmask[e];
        float lpe = lprob[b * NTOK + mem];
        float z[4];
#pragma unroll
        for (int m = 0; m < 4; ++m) {
            float acc = b1[m];
#pragma unroll
            for (int d = 0; d < 5; ++d) acc += pre_table[pe * 5 + d] * w1[d * 4 + m];
            z[m] = acc;
        }
        float mean = (z[0] + z[1] + z[2] + z[3]) * 0.25f;
        float var = 0.0f;
#pragma unroll
        for (int m = 0; m < 4; ++m) { float d = z[m] - mean; var += d * d; }
        float rstd = rsqrtf(var * 0.25f + 1e-5f);
        float sc = lpe * cm;
        float wv[4];
#pragma unroll
        for (int m = 0; m < 4; ++m) {
            float y = (z[m] - mean) * rstd * g1[m] + bb1[m];
            wv[m] = 0.5f * y * (1.0f + erff(y * 0.70710678118654752f)) * sc;
        }
        w_s[tid] = make_float4(wv[0], wv[1], wv[2], wv[3]);
        mem_s[tid] = mem;
    }
    __syncthreads();

    float acc[16];
#pragma unroll
    for (int i = 0; i < 16; ++i) acc[i] = 0.0f;
    const u16* fbase = featb + (size_t)b * NTOK * DIM + lane * 4;
    int k0 = wave * 12;
#pragma unroll
    for (int kk = 0; kk < 12; ++kk) {
        int k = k0 + kk;
        uint2 d = *(const uint2*)(fbase + (size_t)mem_s[k] * DIM);
        float4 w = w_s[k];
        float c0 = asf(d.x << 16);
        float c1 = asf(d.x & 0xFFFF0000u);
        float c2 = asf(d.y << 16);
        float c3 = asf(d.y & 0xFFFF0000u);
        acc[0]  += w.x * c0; acc[1]  += w.y * c0; acc[2]  += w.z * c0; acc[3]  += w.w * c0;
        acc[4]  += w.x * c1; acc[5]  += w.y * c1; acc[6]  += w.z * c1; acc[7]  += w.w * c1;
        acc[8]  += w.x * c2; acc[9]  += w.y * c2; acc[10] += w.z * c2; acc[11] += w.w * c2;
        acc[12] += w.x * c3; acc[13] += w.y * c3; acc[14] += w.z * c3; acc[15] += w.w * c3;
    }
    float* pp = &partials[(wave * 64 + lane) * 16];
#pragma unroll
    for (int i = 0; i < 4; ++i)
        *(float4*)(pp + i * 4) = make_float4(acc[i * 4], acc[i * 4 + 1],
                                             acc[i * 4 + 2], acc[i * 4 + 3]);
    __syncthreads();

    int c = tid;
    float a[4] = {0.f, 0.f, 0.f, 0.f};
#pragma unroll
    for (int w = 0; w < 4; ++w) {
        float4 v = *(const float4*)&partials[(w * 64 + (c >> 2)) * 16 + (c & 3) * 4];
        a[0] += v.x; a[1] += v.y; a[2] += v.z; a[3] += v.w;
    }

    float s1 = a[0] + a[1] + a[2] + a[3];
    float s2 = a[0] * a[0] + a[1] * a[1] + a[2] * a[2] + a[3] * a[3];
#pragma unroll
    for (int off = 32; off > 0; off >>= 1) {
        s1 += __shfl_down(s1, off, 64);
        s2 += __shfl_down(s2, off, 64);
    }
    if (lane == 0) { red[wave] = s1; red[4 + wave] = s2; }
    __syncthreads();
    if (tid == 0) {
        float S = red[0] + red[1] + red[2] + red[3];
        float Q = red[4] + red[5] + red[6] + red[7];
        float mean = S * (1.0f / 1024.0f);
        float var = fmaxf(Q * (1.0f / 1024.0f) - mean * mean, 0.0f);
        red[8] = mean; red[9] = rsqrtf(var + 1e-5f);
    }
    __syncthreads();
    float mean = red[8], rstd = red[9];
    u16* Xp = xdst + (size_t)t * 1024;
#pragma unroll
    for (int m = 0; m < 4; ++m) {
        int cc = m * 256 + c;
        float v = (a[m] - mean) * rstd * norm_g[cc] + norm_b[cc];
        Xp[cc] = f2bf(v);
    }
}

// ---- K5 v2: LDS-tiled GEMM X(12544x1024 bf16) @ linT(512x1024 bf16)^T -----
#define GROW 40   // padded LDS row stride (halves)
__global__ __launch_bounds__(256) void gemm_tile_kernel(
    const u16* __restrict__ xws, const u16* __restrict__ linT,
    const float* __restrict__ lin_b, float* __restrict__ out) {
    __shared__ __align__(16) u16 As[64 * GROW];     // 5.1 KB
    __shared__ __align__(16) u16 Bs[128 * GROW];    // 10.2 KB
    int tid = threadIdx.x;
    int wave = tid >> 6, lane = tid & 63;
    int l15 = lane & 15, quad = lane >> 4;
    int wm = wave >> 1, wn = wave & 1;
    int m0 = blockIdx.x * 64, n0 = blockIdx.y * 128;
    int sr = tid >> 2, sk = (tid & 3) * 8;

    const u16* Ap  = xws + (size_t)(m0 + sr) * 1024 + sk;
    const u16* Bp0 = linT + (size_t)(n0 + sr) * 1024 + sk;
    const u16* Bp1 = linT + (size_t)(n0 + 64 + sr) * 1024 + sk;

    floatx4 acc[2][4] = {};
    for (int kk = 0; kk < 1024; kk += 32) {
        uint4 av = *(const uint4*)(Ap + kk);
        uint4 b0 = *(const uint4*)(Bp0 + kk);
        uint4 b1 = *(const uint4*)(Bp1 + kk);
        __syncthreads();
        *(uint4*)&As[sr * GROW + sk] = av;
        *(uint4*)&Bs[sr * GROW + sk] = b0;
        *(uint4*)&Bs[(64 + sr) * GROW + sk] = b1;
        __syncthreads();
        bf16x8 af[2], bfv[4];
#pragma unroll
        for (int mi = 0; mi < 2; ++mi)
            af[mi] = *(const bf16x8*)&As[(wm * 32 + mi * 16 + l15) * GROW + quad * 8];
#pragma unroll
        for (int ni = 0; ni < 4; ++ni)
            bfv[ni] = *(const bf16x8*)&Bs[(wn * 64 + ni * 16 + l15) * GROW + quad * 8];
#pragma unroll
        for (int mi = 0; mi < 2; ++mi)
#pragma unroll
            for (int ni = 0; ni < 4; ++ni)
                acc[mi][ni] = __builtin_amdgcn_mfma_f32_16x16x32_bf16(
                    af[mi], bfv[ni], acc[mi][ni], 0, 0, 0);
    }
#pragma unroll
    for (int ni = 0; ni < 4; ++ni) {
        int col = n0 + wn * 64 + ni * 16 + l15;
        float bias = lin_b[col];
#pragma unroll
        for (int mi = 0; mi < 2; ++mi)
#pragma unroll
            for (int reg = 0; reg < 4; ++reg) {
                int row = m0 + wm * 32 + mi * 16 + quad * 4 + reg;
                out[(size_t)row * OUTD + col] = acc[mi][ni][reg] + bias;
            }
    }
}

// ---- fallback kernels (zero-workspace, round-3 proven) --------------------
__global__ __launch_bounds__(256) void key_kernel(
    const float* __restrict__ lprob, u64* __restrict__ keys) {
    int g = blockIdx.x * 256 + threadIdx.x;
    int n = g % NTOK;
    keys[g] = f_to_key(make_f(lprob[g], n), n);
}

__global__ __launch_bounds__(256) void partial_rank_kernel(
    const u64* __restrict__ keys, u32* __restrict__ part) {
    int b = blockIdx.y, z = blockIdx.z;
    int n = blockIdx.x * 256 + threadIdx.x;
    u64 my = keys[b * NTOK + n];
    const u64* kb = keys + b * NTOK + z * QTR;
    u32 cnt = 0;
    for (int t = 0; t < QTR; t += 8) {
#pragma unroll
        for (int j = 0; j < 8; ++j) cnt += (kb[t + j] > my) ? 1u : 0u;
    }
    part[(z * NB + b) * NTOK + n] = cnt;
}

__global__ __launch_bounds__(256) void finalize_kernel(
    const u32* __restrict__ part, float* __restrict__ pos_out) {
    int b = blockIdx.y;
    int n = blockIdx.x * 256 + threadIdx.x;
    int g = b * NTOK + n;
    u32 rank = part[g] + part[(NB + b) * NTOK + n] +
               part[(2 * NB + b) * NTOK + n] + part[(3 * NB + b) * NTOK + n];
    int i = n / GW, j = n % GW;
    if (rank < SAMPLEN) {
        int slot = b * KEEPN + (int)rank;
        pos_out[slot * 2 + 0] = (float)i;
        pos_out[slot * 2 + 1] = (float)j;
    }
    if (((i | j) & 3) == 0) {
        int r = (i >> 2) * 28 + (j >> 2);
        int slot = b * KEEPN + SAMPLEN + r;
        pos_out[slot * 2 + 0] = (float)i;
        pos_out[slot * 2 + 1] = (float)j;
    }
}

__global__ __launch_bounds__(256) void token_fb_kernel(
    const float* __restrict__ pos_in, u16* __restrict__ xdst,
    const int* __restrict__ member_idx, const int* __restrict__ pe_idx,
    const float* __restrict__ cmask, const float* __restrict__ lprob,
    const float* __restrict__ featf, const float* __restrict__ pre_table,
    const float* __restrict__ w1, const float* __restrict__ b1,
    const float* __restrict__ g1, const float* __restrict__ bb1,
    const float* __restrict__ norm_g, const float* __restrict__ norm_b) {
    int t = blockIdx.x;
    int b = t / KEEPN;
    int tid = threadIdx.x;
    __shared__ int mem_s[NBHD];
    __shared__ float4 w_s[NBHD];
    __shared__ float red[10];

    int n_src = (int)pos_in[t * 2 + 0] * GW + (int)pos_in[t * 2 + 1];

    if (tid < NBHD) {
        int e = (b * NTOK + n_src) * NBHD + tid;
        int mem = member_idx[e];
        int pe = pe_idx[e];
        float cm = cmask[e];
        float lpe = lprob[b * NTOK + mem];
        float z[4];
#pragma unroll
        for (int m = 0; m < 4; ++m) {
            float acc = b1[m];
#pragma unroll
            for (int d = 0; d < 5; ++d) acc += pre_table[pe * 5 + d] * w1[d * 4 + m];
            z[m] = acc;
        }
        float mean = (z[0] + z[1] + z[2] + z[3]) * 0.25f;
        float var = 0.0f;
#pragma unroll
        for (int m = 0; m < 4; ++m) { float d = z[m] - mean; var += d * d; }
        float rstd = rsqrtf(var * 0.25f + 1e-5f);
        float sc = lpe * cm;
        float wv[4];
#pragma unroll
        for (int m = 0; m < 4; ++m) {
            float y = (z[m] - mean) * rstd * g1[m] + bb1[m];
            wv[m] = 0.5f * y * (1.0f + erff(y * 0.70710678118654752f)) * sc;
        }
        w_s[tid] = make_float4(wv[0], wv[1], wv[2], wv[3]);
        mem_s[tid] = mem;
    }
    __syncthreads();

    float a0 = 0.f, a1 = 0.f, a2 = 0.f, a3 = 0.f;
    size_t base = (size_t)b * NTOK * DIM + tid;
#pragma unroll 8
    for (int k = 0; k < NBHD; ++k) {
        float g = featf[base + (size_t)mem_s[k] * DIM];
        float4 w = w_s[k];
        a0 += w.x * g; a1 += w.y * g; a2 += w.z * g; a3 += w.w * g;
    }
    float s1 = a0 + a1 + a2 + a3;
    float s2 = a0 * a0 + a1 * a1 + a2 * a2 + a3 * a3;
#pragma unroll
    for (int off = 32; off > 0; off >>= 1) {
        s1 += __shfl_down(s1, off, 64);
        s2 += __shfl_down(s2, off, 64);
    }
    int wave = tid >> 6, lane = tid & 63;
    if (lane == 0) { red[wave] = s1; red[4 + wave] = s2; }
    __syncthreads();
    if (tid == 0) {
        float S = red[0] + red[1] + red[2] + red[3];
        float Q = red[4] + red[5] + red[6] + red[7];
        float mean = S * (1.0f / 1024.0f);
        float var = fmaxf(Q * (1.0f / 1024.0f) - mean * mean, 0.0f);
        red[8] = mean; red[9] = rsqrtf(var + 1e-5f);
    }
    __syncthreads();
    float mean = red[8], rstd = red[9];
    float acc4[4] = {a0, a1, a2, a3};
    u16* Xp = xdst + (size_t)t * 1024;
#pragma unroll
    for (int m = 0; m < 4; ++m) {
        int cc = m * 256 + tid;
        float v = (acc4[m] - mean) * rstd * norm_g[cc] + norm_b[cc];
        Xp[cc] = f2bf(v);
    }
}

__global__ __launch_bounds__(256) void gemm_inplace_kernel(
    const float* __restrict__ lin_w, const float* __restrict__ lin_b,
    float* __restrict__ out) {
    __shared__ __align__(16) u16 Bs[BLKN * BROW];
    int tile_m = blockIdx.x;
    int nblk = blockIdx.y;
    int tid = threadIdx.x;
    int wave = tid >> 6, lane = tid & 63;
    int l15 = lane & 15, quad = lane >> 4;

    const u16* Xbase = (const u16*)out;
    floatx4 acc[8][4] = {};

    for (int kk = 0; kk < 1024; kk += 32) {
        __syncthreads();
#pragma unroll
        for (int it = 0; it < 4; ++it) {
            int task = it * 256 + tid;
            int kp = task >> 6;
            int ng = task & 63;
            int k = kp * 2;
            int n0 = nblk * BLKN + ng * 4;
            float4 fa = *(const float4*)&lin_w[(size_t)(kk + k) * OUTD + n0];
            float4 fb = *(const float4*)&lin_w[(size_t)(kk + k + 1) * OUTD + n0];
            u16* bp = &Bs[(ng * 4) * BROW + k];
            *(u32*)(bp + 0 * BROW) = (u32)f2bf(fa.x) | ((u32)f2bf(fb.x) << 16);
            *(u32*)(bp + 1 * BROW) = (u32)f2bf(fa.y) | ((u32)f2bf(fb.y) << 16);
            *(u32*)(bp + 2 * BROW) = (u32)f2bf(fa.z) | ((u32)f2bf(fb.z) << 16);
            *(u32*)(bp + 3 * BROW) = (u32)f2bf(fa.w) | ((u32)f2bf(fb.w) << 16);
        }
        __syncthreads();
        bf16x8 bfrag[4];
#pragma unroll
        for (int ni = 0; ni < 4; ++ni)
            bfrag[ni] = *(const bf16x8*)&Bs[(wave * 64 + ni * 16 + l15) * BROW + quad * 8];
#pragma unroll
        for (int mi = 0; mi < 8; ++mi) {
            int row = tile_m * BLKM + mi * 16 + l15;
            bf16x8 af = *(const bf16x8*)&Xbase[(size_t)row * 1024 + kk + quad * 8];
#pragma unroll
            for (int ni = 0; ni < 4; ++ni)
                acc[mi][ni] = __builtin_amdgcn_mfma_f32_16x16x32_bf16(
                    af, bfrag[ni], acc[mi][ni], 0, 0, 0);
        }
    }
    __syncthreads();
#pragma unroll
    for (int mi = 0; mi < 8; ++mi)
#pragma unroll
        for (int ni = 0; ni < 4; ++ni) {
            int col = nblk * BLKN + wave * 64 + ni * 16 + l15;
            float bias = lin_b[col];
#pragma unroll
            for (int reg = 0; reg < 4; ++reg) {
                int row = tile_m * BLKM + mi * 16 + quad * 4 + reg;
                out[(size_t)row * OUTD + col] = acc[mi][ni][reg] + bias;
            }
        }
}

extern "C" void kernel_launch(void* const* d_in, const int* in_sizes, int n_in,
                              void* d_out, int out_size, void* d_ws, size_t ws_size,
                              hipStream_t stream) {
    const float* feat     = (const float*)d_in[1];
    const int* member_idx = (const int*)d_in[2];
    const float* cmask    = (const float*)d_in[3];
    const float* lprob    = (const float*)d_in[4];
    const int* pe_idx     = (const int*)d_in[6];
    const float* pre_table= (const float*)d_in[8];
    const float* w1       = (const float*)d_in[9];
    const float* b1       = (const float*)d_in[10];
    const float* g1       = (const float*)d_in[11];
    const float* bb1      = (const float*)d_in[12];
    const float* norm_g   = (const float*)d_in[13];
    const float* norm_b   = (const float*)d_in[14];
    const float* lin_w    = (const float*)d_in[15];
    const float* lin_b    = (const float*)d_in[16];

    float* pos_out = (float*)d_out;
    float* out     = pos_out + POSN;

    if (ws_size >= WS_NEED) {
        char* ws = (char*)d_ws;
        u16* featb = (u16*)ws;
        u16* xws   = (u16*)(ws + FEATB_BYTES);
        u16* linT  = (u16*)(ws + FEATB_BYTES + XWS_BYTES);
        u64* slots = (u64*)(ws + FEATB_BYTES + XWS_BYTES + LINT_BYTES);
        u32* hist  = (u32*)(ws + FEATB_BYTES + XWS_BYTES + LINT_BYTES + KEYS_BYTES);
        u32* base  = hist + NB * NBKT;
        u32* curs  = base + NB * NBKT;

        feat_cvt_kernel<<<12544, 256, 0, stream>>>(feat, featb);
        linT_cvt_kernel<<<dim3(16, 8), 256, 0, stream>>>(lin_w, linT);
        zero_hist_kernel<<<256, 256, 0, stream>>>(hist);
        hist_kernel<<<(NB * NTOK) / 256, 256, 0, stream>>>(lprob, hist);
        prefix_kernel<<<NB, 1024, 0, stream>>>(hist, base, curs);
        scatter_kernel<<<(NB * NTOK) / 256, 256, 0, stream>>>(lprob, curs, slots);
        rank_finalize_kernel<<<(NB * NTOK) / 256, 256, 0, stream>>>(
            lprob, hist, base, slots, pos_out);
        token_v2_kernel<<<NB * KEEPN, 256, 0, stream>>>(
            pos_out, xws, member_idx, pe_idx, cmask, lprob, featb,
            pre_table, w1, b1, g1, bb1, norm_g, norm_b);
        gemm_tile_kernel<<<dim3(196, 4), 256, 0, stream>>>(xws, linT, lin_b, out);
    } else {
        u64* keys = (u64*)out;
        u32* part = (u32*)((char*)out + 401408);

        key_kernel<<<(NB * NTOK) / 256, 256, 0, stream>>>(lprob, keys);
        partial_rank_kernel<<<dim3(49, NB, 4), 256, 0, stream>>>(keys, part);
        finalize_kernel<<<dim3(49, NB), 256, 0, stream>>>(part, pos_out);
        token_fb_kernel<<<NB * KEEPN, 256, 0, stream>>>(
            pos_out, (u16*)out, member_idx, pe_idx, cmask, lprob, feat,
            pre_table, w1, b1, g1, bb1, norm_g, norm_b);
        gemm_inplace_kernel<<<dim3(98, 2), 256, 0, stream>>>(lin_w, lin_b, out);
    }
}

// Round 7
// 254.116 us; speedup vs baseline: 1.5521x; 1.0011x over previous
//
#include <hip/hip_runtime.h>

typedef unsigned short u16;
typedef unsigned int u32;
typedef unsigned long long u64;

#define NB 4
#define NTOK 12544
#define NBHD 48
#define DIM 256
#define OUTD 512
#define KEEPN 3136
#define SAMPLEN 2352
#define RESN 784
#define GW 112
#define POSN (NB * KEEPN * 2)   // 25088 floats
#define QTR (NTOK / 4)          // 3136
#define NBKT 16384

// fallback in-place GEMM tiling
#define BLKM 128
#define BLKN 256
#define BROW 40

// ws fast-path layout (bytes)
#define FEATB_BYTES (25690112ull)                 // 4*12544*256*2
#define XWS_BYTES   (25690112ull)                 // 12544*1024*2
#define LINT_BYTES  (1048576ull)                  // 512*1024*2
#define KEYS_BYTES  (401408ull)                   // slots: 4*12544*8
#define PART_BYTES  (802816ull)                   // hist+base+cursor: 786432 used
#define WS_NEED (FEATB_BYTES + XWS_BYTES + LINT_BYTES + KEYS_BYTES + PART_BYTES)

__device__ __forceinline__ float bf2f(u16 u) {
    union { u32 i; float f; } v; v.i = ((u32)u) << 16; return v.f;
}
__device__ __forceinline__ float asf(u32 u) {
    union { u32 i; float f; } v; v.i = u; return v.f;
}
__device__ __forceinline__ u16 f2bf(float f) {
    union { u32 i; float f; } v; v.f = f;
    return (u16)((v.i + 0x7FFFu + ((v.i >> 16) & 1u)) >> 16);
}

typedef __bf16 bf16x8 __attribute__((ext_vector_type(8)));
typedef float floatx4 __attribute__((ext_vector_type(4)));

// final_prob, bit-exact vs reference f32 arithmetic
__device__ __forceinline__ float make_f(float lp, int n) {
    int i = n / GW, j = n % GW;
    float f = lp * 4.0f;
    if (((i | j) & 1) == 0) f = 1.0f + f;        // grid_prob (stride 2)
    if (((i | j) & 3) == 0) f = f + (-100.0f);   // reserve penalty (stride 4)
    return f;
}
// key: descending order == top_k order; ties -> lower n first
__device__ __forceinline__ u64 f_to_key(float f, int n) {
    union { float f; u32 u; } v; v.f = f;
    u32 m = (v.u & 0x80000000u) ? ~v.u : (v.u | 0x80000000u);
    return (((u64)m) << 32) | (u64)(0xFFFFFFFFu - (u32)n);
}
__device__ __forceinline__ int f_to_bucket(float f) {
    int b = (int)floorf(f * 3276.8f);            // monotone: [0,5) -> [0,16384)
    return b < 0 ? 0 : (b > NBKT - 1 ? NBKT - 1 : b);
}

// ---- convert feat f32 -> bf16 ---------------------------------------------
__global__ __launch_bounds__(256) void feat_cvt_kernel(
    const float* __restrict__ feat, u16* __restrict__ featb) {
    int t = blockIdx.x * 256 + threadIdx.x;
    float4 v = ((const float4*)feat)[t];
    u64 w = (u64)f2bf(v.x) | ((u64)f2bf(v.y) << 16) |
            ((u64)f2bf(v.z) << 32) | ((u64)f2bf(v.w) << 48);
    ((u64*)featb)[t] = w;
}

// ---- convert+transpose lin_w -> linT (512x1024 bf16); also zero hist ------
__global__ __launch_bounds__(256) void linT_cvt_kernel(
    const float* __restrict__ lin_w, u16* __restrict__ linT,
    u32* __restrict__ hist) {
    __shared__ u16 T[64 * 65];
    int k0 = blockIdx.x * 64, n0 = blockIdx.y * 64;
    int t = threadIdx.x;
    // fused hist zeroing: 128 blocks x 512 entries = 65536
    int bid = blockIdx.y * 16 + blockIdx.x;
    hist[bid * 512 + t] = 0;
    hist[bid * 512 + 256 + t] = 0;
    int r = t >> 2, c4 = (t & 3) * 16;
#pragma unroll
    for (int i = 0; i < 4; ++i) {
        float4 v = *(const float4*)&lin_w[(size_t)(k0 + r) * OUTD + n0 + c4 + i * 4];
        T[(c4 + i * 4 + 0) * 65 + r] = f2bf(v.x);
        T[(c4 + i * 4 + 1) * 65 + r] = f2bf(v.y);
        T[(c4 + i * 4 + 2) * 65 + r] = f2bf(v.z);
        T[(c4 + i * 4 + 3) * 65 + r] = f2bf(v.w);
    }
    __syncthreads();
    int nl = t >> 2, kc = (t & 3) * 16;
    union { uint4 v[2]; u16 h[16]; } u;
#pragma unroll
    for (int i = 0; i < 16; ++i) u.h[i] = T[nl * 65 + kc + i];
    u16* dst = &linT[(size_t)(n0 + nl) * 1024 + k0 + kc];
    *(uint4*)(dst + 0) = u.v[0];
    *(uint4*)(dst + 8) = u.v[1];
}

// ================= selection: exact counting-sort top-k =====================
__global__ __launch_bounds__(256) void hist_kernel(
    const float* __restrict__ lprob, u32* __restrict__ hist) {
    int g = blockIdx.x * 256 + threadIdx.x;        // 196 blocks
    int b = g / NTOK, n = g % NTOK;
    int bkt = f_to_bucket(make_f(lprob[g], n));
    atomicAdd(&hist[b * NBKT + bkt], 1u);
}

// descending exclusive prefix: base[e] = #keys in buckets > e
__global__ __launch_bounds__(1024) void prefix_kernel(
    const u32* __restrict__ hist, u32* __restrict__ base, u32* __restrict__ cursor) {
    int b = blockIdx.x, t = threadIdx.x;
    const u32* h = hist + b * NBKT;
    u32 loc[16], own = 0;
#pragma unroll
    for (int i = 0; i < 16; ++i) { loc[i] = h[t * 16 + i]; own += loc[i]; }
    __shared__ u32 buf[2][1024];
    buf[0][t] = own;
    __syncthreads();
    int src = 0;
    for (int off = 1; off < 1024; off <<= 1) {
        u32 v = buf[src][t] + ((t + off < 1024) ? buf[src][t + off] : 0u);
        buf[src ^ 1][t] = v;
        src ^= 1;
        __syncthreads();
    }
    u32 above = buf[src][t] - own;                 // chunks strictly after t
    u32 suf = 0, bout[16];
    for (int i = 15; i >= 0; --i) { bout[i] = above + suf; suf += loc[i]; }
    u32* bb = base + b * NBKT;
    u32* cc = cursor + b * NBKT;
#pragma unroll
    for (int i = 0; i < 16; ++i) { bb[t * 16 + i] = bout[i]; cc[t * 16 + i] = bout[i]; }
}

__global__ __launch_bounds__(256) void scatter_kernel(
    const float* __restrict__ lprob, u32* __restrict__ cursor,
    u64* __restrict__ slots) {
    int g = blockIdx.x * 256 + threadIdx.x;
    int b = g / NTOK, n = g % NTOK;
    float f = make_f(lprob[g], n);
    int bkt = f_to_bucket(f);
    u32 s = atomicAdd(&cursor[b * NBKT + bkt], 1u);
    slots[b * NTOK + s] = f_to_key(f, n);
}

__global__ __launch_bounds__(256) void rank_finalize_kernel(
    const float* __restrict__ lprob, const u32* __restrict__ hist,
    const u32* __restrict__ base, const u64* __restrict__ slots,
    float* __restrict__ pos_out) {
    int g = blockIdx.x * 256 + threadIdx.x;
    int b = g / NTOK, n = g % NTOK;
    int i = n / GW, j = n % GW;
    if (((i | j) & 3) == 0) {
        // reserve token: rank >= 11760 > SAMPLEN always; fills fixed tail slot
        int r = (i >> 2) * 28 + (j >> 2);
        int slot = b * KEEPN + SAMPLEN + r;
        pos_out[slot * 2 + 0] = (float)i;
        pos_out[slot * 2 + 1] = (float)j;
        return;
    }
    float f = make_f(lprob[g], n);
    int bkt = f_to_bucket(f);
    u32 r0 = base[b * NBKT + bkt];
    if (r0 >= SAMPLEN) return;                     // whole bucket below cut
    u64 my = f_to_key(f, n);
    u32 cnt = hist[b * NBKT + bkt];
    const u64* sl = slots + b * NTOK + r0;
    u32 rank = r0;
    for (u32 s = 0; s < cnt; ++s) rank += (sl[s] > my) ? 1u : 0u;
    if (rank < SAMPLEN) {
        int slot = b * KEEPN + (int)rank;
        pos_out[slot * 2 + 0] = (float)i;
        pos_out[slot * 2 + 1] = (float)j;
    }
}

// ---- K4 v3: row-per-wave gather, XCD batch-affinity, padded partials ------
#define PSTR 20   // partials row stride (floats): 80 B, 16-B aligned, 2-way max
__global__ __launch_bounds__(256) void token_v2_kernel(
    const float* __restrict__ pos_in, u16* __restrict__ xdst,
    const int* __restrict__ member_idx, const int* __restrict__ pe_idx,
    const float* __restrict__ cmask, const float* __restrict__ lprob,
    const u16* __restrict__ featb, const float* __restrict__ pre_table,
    const float* __restrict__ w1, const float* __restrict__ b1,
    const float* __restrict__ g1, const float* __restrict__ bb1,
    const float* __restrict__ norm_g, const float* __restrict__ norm_b) {
    // XCD-affinity swizzle: block i -> xcd i&7 (round-robin dispatch);
    // batch b owns xcds {2b, 2b+1} so per-XCD hot set = 6.4 MB, not 25.7 MB.
    int bi = blockIdx.x;
    int xcd = bi & 7, jj = bi >> 3;                // jj in [0,1568)
    int b = xcd >> 1;
    int t = b * KEEPN + (xcd & 1) * 1568 + jj;
    int tid = threadIdx.x;
    int wave = tid >> 6, lane = tid & 63;
    __shared__ int mem_s[NBHD];
    __shared__ float4 w_s[NBHD];
    __shared__ float partials[4 * 64 * PSTR];      // 20 KB
    __shared__ float red[10];

    int n_src = (int)pos_in[t * 2 + 0] * GW + (int)pos_in[t * 2 + 1];

    if (tid < NBHD) {
        int e = (b * NTOK + n_src) * NBHD + tid;
        int mem = member_idx[e];
        int pe = pe_idx[e];
        float cm = cmask[e];
        float lpe = lprob[b * NTOK + mem];
        float z[4];
#pragma unroll
        for (int m = 0; m < 4; ++m) {
            float acc = b1[m];
#pragma unroll
            for (int d = 0; d < 5; ++d) acc += pre_table[pe * 5 + d] * w1[d * 4 + m];
            z[m] = acc;
        }
        float mean = (z[0] + z[1] + z[2] + z[3]) * 0.25f;
        float var = 0.0f;
#pragma unroll
        for (int m = 0; m < 4; ++m) { float d = z[m] - mean; var += d * d; }
        float rstd = rsqrtf(var * 0.25f + 1e-5f);
        float sc = lpe * cm;
        float wv[4];
#pragma unroll
        for (int m = 0; m < 4; ++m) {
            float y = (z[m] - mean) * rstd * g1[m] + bb1[m];
            wv[m] = 0.5f * y * (1.0f + erff(y * 0.70710678118654752f)) * sc;
        }
        w_s[tid] = make_float4(wv[0], wv[1], wv[2], wv[3]);
        mem_s[tid] = mem;
    }
    __syncthreads();

    float acc[16];
#pragma unroll
    for (int i = 0; i < 16; ++i) acc[i] = 0.0f;
    const u16* fbase = featb + (size_t)b * NTOK * DIM + lane * 4;
    int k0 = wave * 12;
#pragma unroll
    for (int kk = 0; kk < 12; ++kk) {
        int k = k0 + kk;
        uint2 d = *(const uint2*)(fbase + (size_t)mem_s[k] * DIM);
        float4 w = w_s[k];
        float c0 = asf(d.x << 16);
        float c1 = asf(d.x & 0xFFFF0000u);
        float c2 = asf(d.y << 16);
        float c3 = asf(d.y & 0xFFFF0000u);
        acc[0]  += w.x * c0; acc[1]  += w.y * c0; acc[2]  += w.z * c0; acc[3]  += w.w * c0;
        acc[4]  += w.x * c1; acc[5]  += w.y * c1; acc[6]  += w.z * c1; acc[7]  += w.w * c1;
        acc[8]  += w.x * c2; acc[9]  += w.y * c2; acc[10] += w.z * c2; acc[11] += w.w * c2;
        acc[12] += w.x * c3; acc[13] += w.y * c3; acc[14] += w.z * c3; acc[15] += w.w * c3;
    }
    float* pp = &partials[(wave * 64 + lane) * PSTR];
#pragma unroll
    for (int i = 0; i < 4; ++i)
        *(float4*)(pp + i * 4) = make_float4(acc[i * 4], acc[i * 4 + 1],
                                             acc[i * 4 + 2], acc[i * 4 + 3]);
    __syncthreads();

    int c = tid;
    float a[4] = {0.f, 0.f, 0.f, 0.f};
#pragma unroll
    for (int w = 0; w < 4; ++w) {
        float4 v = *(const float4*)&partials[(w * 64 + (c >> 2)) * PSTR + (c & 3) * 4];
        a[0] += v.x; a[1] += v.y; a[2] += v.z; a[3] += v.w;
    }

    float s1 = a[0] + a[1] + a[2] + a[3];
    float s2 = a[0] * a[0] + a[1] * a[1] + a[2] * a[2] + a[3] * a[3];
#pragma unroll
    for (int off = 32; off > 0; off >>= 1) {
        s1 += __shfl_down(s1, off, 64);
        s2 += __shfl_down(s2, off, 64);
    }
    if (lane == 0) { red[wave] = s1; red[4 + wave] = s2; }
    __syncthreads();
    if (tid == 0) {
        float S = red[0] + red[1] + red[2] + red[3];
        float Q = red[4] + red[5] + red[6] + red[7];
        float mean = S * (1.0f / 1024.0f);
        float var = fmaxf(Q * (1.0f / 1024.0f) - mean * mean, 0.0f);
        red[8] = mean; red[9] = rsqrtf(var + 1e-5f);
    }
    __syncthreads();
    float mean = red[8], rstd = red[9];
    u16* Xp = xdst + (size_t)t * 1024;
#pragma unroll
    for (int m = 0; m < 4; ++m) {
        int cc = m * 256 + c;
        float v = (a[m] - mean) * rstd * norm_g[cc] + norm_b[cc];
        Xp[cc] = f2bf(v);
    }
}

// ---- K5 v3: 128x128 LDS-tiled GEMM X @ linT^T + bias ----------------------
#define GROW 40   // padded LDS row stride (halves)
__global__ __launch_bounds__(256) void gemm_tile_kernel(
    const u16* __restrict__ xws, const u16* __restrict__ linT,
    const float* __restrict__ lin_b, float* __restrict__ out) {
    __shared__ __align__(16) u16 As[128 * GROW];    // 10.2 KB
    __shared__ __align__(16) u16 Bs[128 * GROW];    // 10.2 KB
    int tid = threadIdx.x;
    int wave = tid >> 6, lane = tid & 63;
    int l15 = lane & 15, quad = lane >> 4;
    int wm = wave >> 1, wn = wave & 1;
    int m0 = blockIdx.x * 128, n0 = blockIdx.y * 128;
    int sr = tid >> 2, sk = (tid & 3) * 8;          // 64 rows x 4 chunks per pass

    const u16* Ap0 = xws + (size_t)(m0 + sr) * 1024 + sk;
    const u16* Ap1 = Ap0 + (size_t)64 * 1024;
    const u16* Bp0 = linT + (size_t)(n0 + sr) * 1024 + sk;
    const u16* Bp1 = Bp0 + (size_t)64 * 1024;

    floatx4 acc[4][4] = {};
    for (int kk = 0; kk < 1024; kk += 32) {
        uint4 a0 = *(const uint4*)(Ap0 + kk);
        uint4 a1 = *(const uint4*)(Ap1 + kk);
        uint4 b0 = *(const uint4*)(Bp0 + kk);
        uint4 b1 = *(const uint4*)(Bp1 + kk);
        __syncthreads();
        *(uint4*)&As[sr * GROW + sk] = a0;
        *(uint4*)&As[(64 + sr) * GROW + sk] = a1;
        *(uint4*)&Bs[sr * GROW + sk] = b0;
        *(uint4*)&Bs[(64 + sr) * GROW + sk] = b1;
        __syncthreads();
        bf16x8 af[4], bfv[4];
#pragma unroll
        for (int mi = 0; mi < 4; ++mi)
            af[mi] = *(const bf16x8*)&As[(wm * 64 + mi * 16 + l15) * GROW + quad * 8];
#pragma unroll
        for (int ni = 0; ni < 4; ++ni)
            bfv[ni] = *(const bf16x8*)&Bs[(wn * 64 + ni * 16 + l15) * GROW + quad * 8];
#pragma unroll
        for (int mi = 0; mi < 4; ++mi)
#pragma unroll
            for (int ni = 0; ni < 4; ++ni)
                acc[mi][ni] = __builtin_amdgcn_mfma_f32_16x16x32_bf16(
                    af[mi], bfv[ni], acc[mi][ni], 0, 0, 0);
    }
#pragma unroll
    for (int ni = 0; ni < 4; ++ni) {
        int col = n0 + wn * 64 + ni * 16 + l15;
        float bias = lin_b[col];
#pragma unroll
        for (int mi = 0; mi < 4; ++mi)
#pragma unroll
            for (int reg = 0; reg < 4; ++reg) {
                int row = m0 + wm * 64 + mi * 16 + quad * 4 + reg;
                out[(size_t)row * OUTD + col] = acc[mi][ni][reg] + bias;
            }
    }
}

// ---- fallback kernels (zero-workspace, round-3 proven) --------------------
__global__ __launch_bounds__(256) void key_kernel(
    const float* __restrict__ lprob, u64* __restrict__ keys) {
    int g = blockIdx.x * 256 + threadIdx.x;
    int n = g % NTOK;
    keys[g] = f_to_key(make_f(lprob[g], n), n);
}

__global__ __launch_bounds__(256) void partial_rank_kernel(
    const u64* __restrict__ keys, u32* __restrict__ part) {
    int b = blockIdx.y, z = blockIdx.z;
    int n = blockIdx.x * 256 + threadIdx.x;
    u64 my = keys[b * NTOK + n];
    const u64* kb = keys + b * NTOK + z * QTR;
    u32 cnt = 0;
    for (int t = 0; t < QTR; t += 8) {
#pragma unroll
        for (int j = 0; j < 8; ++j) cnt += (kb[t + j] > my) ? 1u : 0u;
    }
    part[(z * NB + b) * NTOK + n] = cnt;
}

__global__ __launch_bounds__(256) void finalize_kernel(
    const u32* __restrict__ part, float* __restrict__ pos_out) {
    int b = blockIdx.y;
    int n = blockIdx.x * 256 + threadIdx.x;
    int g = b * NTOK + n;
    u32 rank = part[g] + part[(NB + b) * NTOK + n] +
               part[(2 * NB + b) * NTOK + n] + part[(3 * NB + b) * NTOK + n];
    int i = n / GW, j = n % GW;
    if (rank < SAMPLEN) {
        int slot = b * KEEPN + (int)rank;
        pos_out[slot * 2 + 0] = (float)i;
        pos_out[slot * 2 + 1] = (float)j;
    }
    if (((i | j) & 3) == 0) {
        int r = (i >> 2) * 28 + (j >> 2);
        int slot = b * KEEPN + SAMPLEN + r;
        pos_out[slot * 2 + 0] = (float)i;
        pos_out[slot * 2 + 1] = (float)j;
    }
}

__global__ __launch_bounds__(256) void token_fb_kernel(
    const float* __restrict__ pos_in, u16* __restrict__ xdst,
    const int* __restrict__ member_idx, const int* __restrict__ pe_idx,
    const float* __restrict__ cmask, const float* __restrict__ lprob,
    const float* __restrict__ featf, const float* __restrict__ pre_table,
    const float* __restrict__ w1, const float* __restrict__ b1,
    const float* __restrict__ g1, const float* __restrict__ bb1,
    const float* __restrict__ norm_g, const float* __restrict__ norm_b) {
    int t = blockIdx.x;
    int b = t / KEEPN;
    int tid = threadIdx.x;
    __shared__ int mem_s[NBHD];
    __shared__ float4 w_s[NBHD];
    __shared__ float red[10];

    int n_src = (int)pos_in[t * 2 + 0] * GW + (int)pos_in[t * 2 + 1];

    if (tid < NBHD) {
        int e = (b * NTOK + n_src) * NBHD + tid;
        int mem = member_idx[e];
        int pe = pe_idx[e];
        float cm = cmask[e];
        float lpe = lprob[b * NTOK + mem];
        float z[4];
#pragma unroll
        for (int m = 0; m < 4; ++m) {
            float acc = b1[m];
#pragma unroll
            for (int d = 0; d < 5; ++d) acc += pre_table[pe * 5 + d] * w1[d * 4 + m];
            z[m] = acc;
        }
        float mean = (z[0] + z[1] + z[2] + z[3]) * 0.25f;
        float var = 0.0f;
#pragma unroll
        for (int m = 0; m < 4; ++m) { float d = z[m] - mean; var += d * d; }
        float rstd = rsqrtf(var * 0.25f + 1e-5f);
        float sc = lpe * cm;
        float wv[4];
#pragma unroll
        for (int m = 0; m < 4; ++m) {
            float y = (z[m] - mean) * rstd * g1[m] + bb1[m];
            wv[m] = 0.5f * y * (1.0f + erff(y * 0.70710678118654752f)) * sc;
        }
        w_s[tid] = make_float4(wv[0], wv[1], wv[2], wv[3]);
        mem_s[tid] = mem;
    }
    __syncthreads();

    float a0 = 0.f, a1 = 0.f, a2 = 0.f, a3 = 0.f;
    size_t base = (size_t)b * NTOK * DIM + tid;
#pragma unroll 8
    for (int k = 0; k < NBHD; ++k) {
        float g = featf[base + (size_t)mem_s[k] * DIM];
        float4 w = w_s[k];
        a0 += w.x * g; a1 += w.y * g; a2 += w.z * g; a3 += w.w * g;
    }
    float s1 = a0 + a1 + a2 + a3;
    float s2 = a0 * a0 + a1 * a1 + a2 * a2 + a3 * a3;
#pragma unroll
    for (int off = 32; off > 0; off >>= 1) {
        s1 += __shfl_down(s1, off, 64);
        s2 += __shfl_down(s2, off, 64);
    }
    int wave = tid >> 6, lane = tid & 63;
    if (lane == 0) { red[wave] = s1; red[4 + wave] = s2; }
    __syncthreads();
    if (tid == 0) {
        float S = red[0] + red[1] + red[2] + red[3];
        float Q = red[4] + red[5] + red[6] + red[7];
        float mean = S * (1.0f / 1024.0f);
        float var = fmaxf(Q * (1.0f / 1024.0f) - mean * mean, 0.0f);
        red[8] = mean; red[9] = rsqrtf(var + 1e-5f);
    }
    __syncthreads();
    float mean = red[8], rstd = red[9];
    float acc4[4] = {a0, a1, a2, a3};
    u16* Xp = xdst + (size_t)t * 1024;
#pragma unroll
    for (int m = 0; m < 4; ++m) {
        int cc = m * 256 + tid;
        float v = (acc4[m] - mean) * rstd * norm_g[cc] + norm_b[cc];
        Xp[cc] = f2bf(v);
    }
}

__global__ __launch_bounds__(256) void gemm_inplace_kernel(
    const float* __restrict__ lin_w, const float* __restrict__ lin_b,
    float* __restrict__ out) {
    __shared__ __align__(16) u16 Bs[BLKN * BROW];
    int tile_m = blockIdx.x;
    int nblk = blockIdx.y;
    int tid = threadIdx.x;
    int wave = tid >> 6, lane = tid & 63;
    int l15 = lane & 15, quad = lane >> 4;

    const u16* Xbase = (const u16*)out;
    floatx4 acc[8][4] = {};

    for (int kk = 0; kk < 1024; kk += 32) {
        __syncthreads();
#pragma unroll
        for (int it = 0; it < 4; ++it) {
            int task = it * 256 + tid;
            int kp = task >> 6;
            int ng = task & 63;
            int k = kp * 2;
            int n0 = nblk * BLKN + ng * 4;
            float4 fa = *(const float4*)&lin_w[(size_t)(kk + k) * OUTD + n0];
            float4 fb = *(const float4*)&lin_w[(size_t)(kk + k + 1) * OUTD + n0];
            u16* bp = &Bs[(ng * 4) * BROW + k];
            *(u32*)(bp + 0 * BROW) = (u32)f2bf(fa.x) | ((u32)f2bf(fb.x) << 16);
            *(u32*)(bp + 1 * BROW) = (u32)f2bf(fa.y) | ((u32)f2bf(fb.y) << 16);
            *(u32*)(bp + 2 * BROW) = (u32)f2bf(fa.z) | ((u32)f2bf(fb.z) << 16);
            *(u32*)(bp + 3 * BROW) = (u32)f2bf(fa.w) | ((u32)f2bf(fb.w) << 16);
        }
        __syncthreads();
        bf16x8 bfrag[4];
#pragma unroll
        for (int ni = 0; ni < 4; ++ni)
            bfrag[ni] = *(const bf16x8*)&Bs[(wave * 64 + ni * 16 + l15) * BROW + quad * 8];
#pragma unroll
        for (int mi = 0; mi < 8; ++mi) {
            int row = tile_m * BLKM + mi * 16 + l15;
            bf16x8 af = *(const bf16x8*)&Xbase[(size_t)row * 1024 + kk + quad * 8];
#pragma unroll
            for (int ni = 0; ni < 4; ++ni)
                acc[mi][ni] = __builtin_amdgcn_mfma_f32_16x16x32_bf16(
                    af, bfrag[ni], acc[mi][ni], 0, 0, 0);
        }
    }
    __syncthreads();
#pragma unroll
    for (int mi = 0; mi < 8; ++mi)
#pragma unroll
        for (int ni = 0; ni < 4; ++ni) {
            int col = nblk * BLKN + wave * 64 + ni * 16 + l15;
            float bias = lin_b[col];
#pragma unroll
            for (int reg = 0; reg < 4; ++reg) {
                int row = tile_m * BLKM + mi * 16 + quad * 4 + reg;
                out[(size_t)row * OUTD + col] = acc[mi][ni][reg] + bias;
            }
        }
}

extern "C" void kernel_launch(void* const* d_in, const int* in_sizes, int n_in,
                              void* d_out, int out_size, void* d_ws, size_t ws_size,
                              hipStream_t stream) {
    const float* feat     = (const float*)d_in[1];
    const int* member_idx = (const int*)d_in[2];
    const float* cmask    = (const float*)d_in[3];
    const float* lprob    = (const float*)d_in[4];
    const int* pe_idx     = (const int*)d_in[6];
    const float* pre_table= (const float*)d_in[8];
    const float* w1       = (const float*)d_in[9];
    const float* b1       = (const float*)d_in[10];
    const float* g1       = (const float*)d_in[11];
    const float* bb1      = (const float*)d_in[12];
    const float* norm_g   = (const float*)d_in[13];
    const float* norm_b   = (const float*)d_in[14];
    const float* lin_w    = (const float*)d_in[15];
    const float* lin_b    = (const float*)d_in[16];

    float* pos_out = (float*)d_out;
    float* out     = pos_out + POSN;

    if (ws_size >= WS_NEED) {
        char* ws = (char*)d_ws;
        u16* featb = (u16*)ws;
        u16* xws   = (u16*)(ws + FEATB_BYTES);
        u16* linT  = (u16*)(ws + FEATB_BYTES + XWS_BYTES);
        u64* slots = (u64*)(ws + FEATB_BYTES + XWS_BYTES + LINT_BYTES);
        u32* hist  = (u32*)(ws + FEATB_BYTES + XWS_BYTES + LINT_BYTES + KEYS_BYTES);
        u32* base  = hist + NB * NBKT;
        u32* curs  = base + NB * NBKT;

        feat_cvt_kernel<<<12544, 256, 0, stream>>>(feat, featb);
        linT_cvt_kernel<<<dim3(16, 8), 256, 0, stream>>>(lin_w, linT, hist);
        hist_kernel<<<(NB * NTOK) / 256, 256, 0, stream>>>(lprob, hist);
        prefix_kernel<<<NB, 1024, 0, stream>>>(hist, base, curs);
        scatter_kernel<<<(NB * NTOK) / 256, 256, 0, stream>>>(lprob, curs, slots);
        rank_finalize_kernel<<<(NB * NTOK) / 256, 256, 0, stream>>>(
            lprob, hist, base, slots, pos_out);
        token_v2_kernel<<<NB * KEEPN, 256, 0, stream>>>(
            pos_out, xws, member_idx, pe_idx, cmask, lprob, featb,
            pre_table, w1, b1, g1, bb1, norm_g, norm_b);
        gemm_tile_kernel<<<dim3(98, 4), 256, 0, stream>>>(xws, linT, lin_b, out);
    } else {
        u64* keys = (u64*)out;
        u32* part = (u32*)((char*)out + 401408);

        key_kernel<<<(NB * NTOK) / 256, 256, 0, stream>>>(lprob, keys);
        partial_rank_kernel<<<dim3(49, NB, 4), 256, 0, stream>>>(keys, part);
        finalize_kernel<<<dim3(49, NB), 256, 0, stream>>>(part, pos_out);
        token_fb_kernel<<<NB * KEEPN, 256, 0, stream>>>(
            pos_out, (u16*)out, member_idx, pe_idx, cmask, lprob, feat,
            pre_table, w1, b1, g1, bb1, norm_g, norm_b);
        gemm_inplace_kernel<<<dim3(98, 2), 256, 0, stream>>>(lin_w, lin_b, out);
    }
}